// Round 12
// baseline (1739.562 us; speedup 1.0000x reference)
//
#include <hip/hip_runtime.h>
#include <hip/hip_bf16.h>
#include <math.h>

typedef __hip_bfloat16 bf16;
typedef __attribute__((ext_vector_type(8))) short bf16x8;
typedef __attribute__((ext_vector_type(4))) float f32x4;

#define MFMA(a,b,c) __builtin_amdgcn_mfma_f32_16x16x32_bf16(a,b,c,0,0,0)

#define B_ 8
#define C_ 3
#define IMG_ 512
#define P_ 16
#define DIM_ 256
#define HEADS_ 8
#define DEPTH_ 4
#define DH_ 32
#define L_ 1024
#define EC_ 64
#define PD_ 1024
#define NPATCH 8192
#define NROWS 65536

__device__ __forceinline__ float ldsel(const void* p, long i, int m){
    return m ? __bfloat162float(((const bf16*)p)[i]) : ((const float*)p)[i];
}
__device__ __forceinline__ float geluf(float x){
    return 0.5f * x * (1.0f + erff(x * 0.70710678118654752f));
}
__device__ __forceinline__ short f2bf_s(float f){
    bf16 h = __float2bfloat16(f); return *(short*)&h;
}
__device__ __forceinline__ float bfs2f(short s){
    bf16 h = *(bf16*)&s; return __bfloat162float(h);
}
__device__ __forceinline__ void split2(float f, short& hi, short& lo){
    hi = f2bf_s(f);
    lo = f2bf_s(f - bfs2f(hi));
}
__device__ __forceinline__ void split3(float f, short& h, short& m, short& l){
    h = f2bf_s(f); float r1 = f - bfs2f(h);
    m = f2bf_s(r1); float r2 = r1 - bfs2f(m);
    l = f2bf_s(r2);
}

// Runtime input-dtype detection (bf16 vs fp32): exponent-byte histogram.
__global__ void detect_kernel(const void* __restrict__ img, int* __restrict__ flag)
{
    const unsigned* w = (const unsigned*)img;
    const int t = threadIdx.x;
    int c = 0;
    #pragma unroll
    for (int i = 0; i < 4; i++){
        unsigned b = (w[t*4 + i] >> 7) & 0xFFu;
        if (b >= 100u && b <= 145u) c++;
    }
    #pragma unroll
    for (int o = 32; o > 0; o >>= 1) c += __shfl_xor(c, o, 64);
    if (t == 0) *flag = (c > 180) ? 1 : 0;
}

// ---------------------------------------------------------------------------
// Conv stats pass: lane = output channel (broadcast inp reads, conflict-free),
// zero-padded 18x18 tile (branch-free, bitwise-identical conv values).
// ---------------------------------------------------------------------------
__global__ void conv_stats_kernel(const int* __restrict__ fl,
                                  const void* __restrict__ img,
                                  const void* __restrict__ conv_w,
                                  const void* __restrict__ conv_b,
                                  float* __restrict__ psum, float* __restrict__ psq)
{
    const int f = *fl;
    __shared__ float inp[3*18*18];
    __shared__ float wl[EC_*27];
    __shared__ float reds[4][64], redq[4][64];
    const int n = blockIdx.x, t = threadIdx.x;
    const int b = n >> 10, l = n & 1023;
    const int gy = l >> 5, gx = l & 31;
    const int w = t >> 6, o = t & 63;
    for (int e = t; e < EC_*27; e += 256) wl[e] = ldsel(conv_w, e, f);
    for (int e = t; e < 3*18*18; e += 256){
        int c = e / 324, rem = e - c*324;
        int y = rem / 18, x = rem - y*18;
        float v = 0.f;
        if (y >= 1 && y <= 16 && x >= 1 && x <= 16)
            v = ldsel(img, ((long)(b*C_+c)*IMG_ + gy*P_ + (y-1))*IMG_ + gx*P_ + (x-1), f);
        inp[e] = v;
    }
    __syncthreads();
    float wr[27];
    #pragma unroll
    for (int i = 0; i < 27; i++) wr[i] = wl[o*27 + i];
    const float cb = ldsel(conv_b, o, f);
    float s = 0.f, sq = 0.f;
    #pragma unroll
    for (int i = 0; i < 16; i++){
        int pix = w*16 + i;
        int oy = pix >> 3, ox = pix & 7;
        float acc = cb;
        #pragma unroll
        for (int c = 0; c < 3; c++)
        #pragma unroll
        for (int ky = 0; ky < 3; ky++)
        #pragma unroll
        for (int kx = 0; kx < 3; kx++)
            acc += inp[c*324 + (2*oy+ky)*18 + 2*ox+kx] * wr[c*9+ky*3+kx];
        s += acc; sq += acc*acc;
    }
    reds[w][o] = s; redq[w][o] = sq;
    __syncthreads();
    if (t < 64){
        float S = reds[0][t]+reds[1][t]+reds[2][t]+reds[3][t];
        float Q = redq[0][t]+redq[1][t]+redq[2][t]+redq[3][t];
        psum[(long)t*NPATCH + n] = S;
        psq [(long)t*NPATCH + n] = Q;
    }
}

__global__ void bn_stats_kernel(const int* __restrict__ fl,
                                const float* __restrict__ psum, const float* __restrict__ psq,
                                const void* __restrict__ bn_g, const void* __restrict__ bn_b,
                                float* __restrict__ scaleA, float* __restrict__ biasA)
{
    const int f = *fl;
    __shared__ float rs[256], rq[256];
    const int o = blockIdx.x, t = threadIdx.x;
    float S = 0.f, Q = 0.f;
    for (int n = t; n < NPATCH; n += 256){ S += psum[(long)o*NPATCH+n]; Q += psq[(long)o*NPATCH+n]; }
    rs[t] = S; rq[t] = Q; __syncthreads();
    for (int st = 128; st > 0; st >>= 1){
        if (t < st){ rs[t] += rs[t+st]; rq[t] += rq[t+st]; }
        __syncthreads();
    }
    if (t == 0){
        const float Ninv = 1.0f / (float)((long)NPATCH * 64);
        float mean = rs[0] * Ninv;
        float var  = rq[0] * Ninv - mean*mean;
        float rstd = rsqrtf(var + 1e-5f);
        float sc = ldsel(bn_g, o, f) * rstd;
        scaleA[o] = sc;
        biasA[o]  = ldsel(bn_b, o, f) - mean*sc;
    }
}

// Recompute conv (bitwise-identical), BN + exact GELU + maxpool; emits x0 splits.
__global__ void bn_gelu_pool_kernel(const int* __restrict__ fl,
                                    const void* __restrict__ img,
                                    const void* __restrict__ conv_w,
                                    const void* __restrict__ conv_b,
                                    const float* __restrict__ scaleA,
                                    const float* __restrict__ biasA,
                                    short* __restrict__ x0h, short* __restrict__ x0m,
                                    short* __restrict__ x0l)
{
    const int f = *fl;
    __shared__ float inp[3*18*18];
    __shared__ float wl[EC_*27];
    __shared__ float cosb[64][65];
    __shared__ float poolb[64*17];
    __shared__ float sA[64], bA[64];
    const int n = blockIdx.x, t = threadIdx.x;
    const int b = n >> 10, l = n & 1023;
    const int gy = l >> 5, gx = l & 31;
    const int w = t >> 6, o = t & 63;
    for (int e = t; e < EC_*27; e += 256) wl[e] = ldsel(conv_w, e, f);
    for (int e = t; e < 3*18*18; e += 256){
        int c = e / 324, rem = e - c*324;
        int y = rem / 18, x = rem - y*18;
        float v = 0.f;
        if (y >= 1 && y <= 16 && x >= 1 && x <= 16)
            v = ldsel(img, ((long)(b*C_+c)*IMG_ + gy*P_ + (y-1))*IMG_ + gx*P_ + (x-1), f);
        inp[e] = v;
    }
    if (t < 64){ sA[t] = scaleA[t]; bA[t] = biasA[t]; }
    __syncthreads();
    float wr[27];
    #pragma unroll
    for (int i = 0; i < 27; i++) wr[i] = wl[o*27 + i];
    const float cb = ldsel(conv_b, o, f);
    const float sc = sA[o], bb = bA[o];
    #pragma unroll
    for (int i = 0; i < 16; i++){
        int pix = w*16 + i;
        int oy = pix >> 3, ox = pix & 7;
        float acc = cb;
        #pragma unroll
        for (int c = 0; c < 3; c++)
        #pragma unroll
        for (int ky = 0; ky < 3; ky++)
        #pragma unroll
        for (int kx = 0; kx < 3; kx++)
            acc += inp[c*324 + (2*oy+ky)*18 + 2*ox+kx] * wr[c*9+ky*3+kx];
        cosb[pix][o] = geluf(acc*sc + bb);
    }
    __syncthreads();
    #pragma unroll
    for (int j = 0; j < 4; j++){
        int pp = w*4 + j;
        int py = pp >> 2, px = pp & 3;
        int y0 = max(0, 2*py-1), y1 = min(7, 2*py+1);
        int xs = max(0, 2*px-1), x1 = min(7, 2*px+1);
        float mx = -INFINITY;
        for (int y = y0; y <= y1; y++)
            for (int x = xs; x <= x1; x++)
                mx = fmaxf(mx, cosb[y*8+x][o]);
        poolb[o*17 + pp] = mx;
    }
    __syncthreads();
    for (int e = t; e < 1024; e += 256){
        float v = poolb[(e>>4)*17 + (e&15)];
        short h, m, lo; split3(v, h, m, lo);
        long idx = (long)n*PD_ + e;
        x0h[idx] = h; x0m[idx] = m; x0l[idx] = lo;
    }
}

// Elementwise 3-term split (adjacency).
__global__ void split_adj_kernel(const int* __restrict__ fl, const void* __restrict__ adj,
                                 short* __restrict__ Ah, short* __restrict__ Am,
                                 short* __restrict__ Al)
{
    const int f = *fl;
    long i = (long)blockIdx.x*256 + threadIdx.x;
    short h, m, l; split3(ldsel(adj, i, f), h, m, l);
    Ah[i] = h; Am[i] = m; Al[i] = l;
}

// Transpose + 3-term split: out[c][r] = src[r][c].  grid (C/64, R/64, Z).
__global__ void tsplit_kernel(const int* __restrict__ fl, const void* __restrict__ src,
                              long soff, long zsStride, int R, int Ccols,
                              short* __restrict__ oh, short* __restrict__ om,
                              short* __restrict__ ol, long ozStride)
{
    __shared__ float tile[64][65];
    const int f = *fl;
    const int t = threadIdx.x;
    const int zz = blockIdx.z;
    const long sb = soff + (long)zz*zsStride;
    oh += (long)zz*ozStride; om += (long)zz*ozStride; ol += (long)zz*ozStride;
    const int c0 = blockIdx.x*64, r0 = blockIdx.y*64;
    for (int e = t; e < 4096; e += 256){
        int r = e >> 6, c = e & 63;
        tile[r][c] = ldsel(src, sb + (long)(r0+r)*Ccols + c0+c, f);
    }
    __syncthreads();
    const int ch = t >> 2, lg = t & 3;
    long ob = (long)(c0+ch)*R + r0 + lg*16;
    bf16x8 h0,h1,m0,m1,l0,l1;
    #pragma unroll
    for (int i = 0; i < 8; i++){
        short h,m,l;
        split3(tile[lg*16+i][ch], h,m,l);    h0[i]=h; m0[i]=m; l0[i]=l;
        split3(tile[lg*16+8+i][ch], h,m,l);  h1[i]=h; m1[i]=m; l1[i]=l;
    }
    *(bf16x8*)(oh+ob) = h0; *(bf16x8*)(oh+ob+8) = h1;
    *(bf16x8*)(om+ob) = m0; *(bf16x8*)(om+ob+8) = m1;
    *(bf16x8*)(ol+ob) = l0; *(bf16x8*)(ol+ob+8) = l1;
}

// ---------------------------------------------------------------------------
// Fused LayerNorm + transpose-split: x (rows of 256) -> xn fp32 row-major AND
// xT (b,256,L) 3-term splits.  32 rows/block, 256 blocks.
// ---------------------------------------------------------------------------
__global__ void ln_repack_kernel(const int* __restrict__ fl,
                                 const float* __restrict__ x,
                                 const void* __restrict__ g, long goff,
                                 const void* __restrict__ beta, long boff,
                                 float* __restrict__ xn,
                                 short* __restrict__ xTh, short* __restrict__ xTm,
                                 short* __restrict__ xTl)
{
    __shared__ float tile[32][257];
    __shared__ float gs[256], bs[256];
    __shared__ float pm[8][32], pq[8][32];
    __shared__ float mean_s[32], rstd_s[32];
    const int f = *fl;
    const int t = threadIdx.x;
    const int r0 = blockIdx.x*32;            // global row (b*L + l)
    const int b = r0 >> 10, l0 = r0 & 1023;
    gs[t] = ldsel(g, goff + t, f);
    bs[t] = ldsel(beta, boff + t, f);
    for (int e = t; e < 32*256; e += 256){
        int r = e >> 8, c = e & 255;
        tile[r][c] = x[(long)(r0+r)*DIM_ + c];
    }
    __syncthreads();
    {
        int row = t & 31, part = t >> 5;
        float s = 0.f, q = 0.f;
        #pragma unroll
        for (int c = 0; c < 32; c++){
            float v = tile[row][part*32 + c];
            s += v; q += v*v;
        }
        pm[part][row] = s; pq[part][row] = q;
    }
    __syncthreads();
    if (t < 32){
        float S = 0.f, Q = 0.f;
        #pragma unroll
        for (int p2 = 0; p2 < 8; p2++){ S += pm[p2][t]; Q += pq[p2][t]; }
        float mean = S * (1.0f/256.0f);
        float var  = Q * (1.0f/256.0f) - mean*mean;
        mean_s[t] = mean;
        rstd_s[t] = rsqrtf(var + 1e-5f);
    }
    __syncthreads();
    for (int e = t; e < 32*256; e += 256){
        int r = e >> 8, c = e & 255;
        float v = (tile[r][c] - mean_s[r])*rstd_s[r]*gs[c] + bs[c];
        tile[r][c] = v;
        xn[(long)(r0+r)*DIM_ + c] = v;
    }
    __syncthreads();
    // transposed split emit: 2 passes of 128 cols; 2 lanes cover the 32 rows
    const int half = t & 1, cB = t >> 1;
    #pragma unroll
    for (int gp = 0; gp < 2; gp++){
        int c = gp*128 + cB;
        long ob = ((long)(b*DIM_) + c)*L_ + l0 + half*16;
        bf16x8 h0, m0, l0v;
        #pragma unroll
        for (int i = 0; i < 8; i++){
            short hh, mm, ll;
            split3(tile[half*16 + i][c], hh, mm, ll);
            h0[i]=hh; m0[i]=mm; l0v[i]=ll;
        }
        *(bf16x8*)(xTh+ob) = h0; *(bf16x8*)(xTm+ob) = m0; *(bf16x8*)(xTl+ob) = l0v;
        bf16x8 h1, m1, l1v;
        #pragma unroll
        for (int i = 0; i < 8; i++){
            short hh, mm, ll;
            split3(tile[half*16 + 8 + i][c], hh, mm, ll);
            h1[i]=hh; m1[i]=mm; l1v[i]=ll;
        }
        *(bf16x8*)(xTh+ob+8) = h1; *(bf16x8*)(xTm+ob+8) = m1; *(bf16x8*)(xTl+ob+8) = l1v;
    }
}

// ---------------------------------------------------------------------------
// Generic MFMA GEMM, fp32-accurate via 3-term bf16 splits (6 products).
// Tile 32 rows x 128 cols; 4 waves = 2 row-strips x 2 col-halves; acc[4].
// Register ping-pong double-buffer.  K % 64 == 0.  (R8/R10-measured best.)
// ---------------------------------------------------------------------------
__global__ __launch_bounds__(256)
void mfma_gemm(const short* __restrict__ Ah, const short* __restrict__ Am,
               const short* __restrict__ Al, long strAb,
               const short* __restrict__ Bh, const short* __restrict__ Bm,
               const short* __restrict__ Bl, long strBb,
               const void* __restrict__ bias, long biasOff, const int* __restrict__ fl,
               const float* __restrict__ Dadd, long strDb,
               float* __restrict__ C, long strCb,
               int N, int K)
{
    const int t = threadIdx.x;
    const int w = t >> 6, lane = t & 63;
    const int mrow = lane & 15, quad = lane >> 4;
    const int wr = w & 1, wc = w >> 1;
    const int s0 = blockIdx.y*32 + wr*16;
    const int n0 = blockIdx.x*128 + wc*64;
    const int z = blockIdx.z;
    const short* Ahp = Ah + (long)z*strAb;
    const short* Amp = Am + (long)z*strAb;
    const short* Alp = Al + (long)z*strAb;
    const short* Bhp = Bh + (long)z*strBb;
    const short* Bmp = Bm + (long)z*strBb;
    const short* Blp = Bl + (long)z*strBb;
    f32x4 acc[4];
    #pragma unroll
    for (int i = 0; i < 4; i++) acc[i] = (f32x4){0.f,0.f,0.f,0.f};

    const long aoff0 = (long)(s0 + mrow)*K + quad*8;
    const long b0    = (long)(n0 + mrow)*K + quad*8;
    const long bstp  = (long)16*K;

    bf16x8 ahA, amA, alA, bhA[4], bmA[4], blA[4];
    ahA = *(const bf16x8*)(Ahp + aoff0);
    amA = *(const bf16x8*)(Amp + aoff0);
    alA = *(const bf16x8*)(Alp + aoff0);
    #pragma unroll
    for (int nt = 0; nt < 4; nt++){
        long bo = b0 + nt*bstp;
        bhA[nt] = *(const bf16x8*)(Bhp + bo);
        bmA[nt] = *(const bf16x8*)(Bmp + bo);
        blA[nt] = *(const bf16x8*)(Blp + bo);
    }
    for (int k0 = 0; k0 < K; k0 += 64){
        bf16x8 ahB, amB, alB, bhB[4], bmB[4], blB[4];
        {
            long an = aoff0 + k0 + 32;
            ahB = *(const bf16x8*)(Ahp + an);
            amB = *(const bf16x8*)(Amp + an);
            alB = *(const bf16x8*)(Alp + an);
            #pragma unroll
            for (int nt = 0; nt < 4; nt++){
                long bo = b0 + nt*bstp + k0 + 32;
                bhB[nt] = *(const bf16x8*)(Bhp + bo);
                bmB[nt] = *(const bf16x8*)(Bmp + bo);
                blB[nt] = *(const bf16x8*)(Blp + bo);
            }
        }
        #pragma unroll
        for (int nt = 0; nt < 4; nt++){
            acc[nt] = MFMA(alA, bhA[nt], acc[nt]);
            acc[nt] = MFMA(amA, bmA[nt], acc[nt]);
            acc[nt] = MFMA(ahA, blA[nt], acc[nt]);
            acc[nt] = MFMA(amA, bhA[nt], acc[nt]);
            acc[nt] = MFMA(ahA, bmA[nt], acc[nt]);
            acc[nt] = MFMA(ahA, bhA[nt], acc[nt]);
        }
        if (k0 + 64 < K){
            long an = aoff0 + k0 + 64;
            ahA = *(const bf16x8*)(Ahp + an);
            amA = *(const bf16x8*)(Amp + an);
            alA = *(const bf16x8*)(Alp + an);
            #pragma unroll
            for (int nt = 0; nt < 4; nt++){
                long bo = b0 + nt*bstp + k0 + 64;
                bhA[nt] = *(const bf16x8*)(Bhp + bo);
                bmA[nt] = *(const bf16x8*)(Bmp + bo);
                blA[nt] = *(const bf16x8*)(Blp + bo);
            }
        }
        #pragma unroll
        for (int nt = 0; nt < 4; nt++){
            acc[nt] = MFMA(alB, bhB[nt], acc[nt]);
            acc[nt] = MFMA(amB, bmB[nt], acc[nt]);
            acc[nt] = MFMA(ahB, blB[nt], acc[nt]);
            acc[nt] = MFMA(amB, bhB[nt], acc[nt]);
            acc[nt] = MFMA(ahB, bmB[nt], acc[nt]);
            acc[nt] = MFMA(ahB, bhB[nt], acc[nt]);
        }
    }
    const int f = *fl;
    #pragma unroll
    for (int nt = 0; nt < 4; nt++)
    #pragma unroll
    for (int r = 0; r < 4; r++){
        long row = s0 + quad*4 + r;
        int col = n0 + nt*16 + mrow;
        float v = acc[nt][r];
        if (bias) v += ldsel(bias, biasOff + col, f);
        if (Dadd) v += Dadd[(long)z*strDb + row*N + col];
        C[(long)z*strCb + row*N + col] = v;
    }
}

// ---------------------------------------------------------------------------
// Fused A@xn GEMM + qk projection.  m = adj @ xn + xn stays in LDS.
// Tile 32 rows x 128 cols; 4 waves; register ping-pong double-buffer.
// grid (2, 32, 8) = 512 blocks, direct blockIdx mapping (R10-measured best;
// R11's XCD remap refuted — working sets already L2-resident).
// Non-last: emits q/k 3-term splits. Last: 2-term splits into d_ws
// (INVARIANT: last-layer attn reads only d_ws).
// ---------------------------------------------------------------------------
__global__ __launch_bounds__(256)
void gemm_axn_qk(const short* __restrict__ Ah, const short* __restrict__ Am,
                 const short* __restrict__ Al,
                 const short* __restrict__ Bh, const short* __restrict__ Bm,
                 const short* __restrict__ Bl,
                 const float* __restrict__ xn, const int* __restrict__ fl,
                 const void* __restrict__ qk_w, long woff,
                 const void* __restrict__ qk_b, long boff,
                 short* __restrict__ qh, short* __restrict__ qm, short* __restrict__ ql,
                 short* __restrict__ kh, short* __restrict__ km, short* __restrict__ kl,
                 short* __restrict__ q2h, short* __restrict__ q2m,
                 short* __restrict__ k2h, short* __restrict__ k2m)
{
    __shared__ float m_lds[32][132];
    __shared__ float wl[32][65];
    __shared__ float bl2[64];
    const int t = threadIdx.x;
    const int w = t >> 6, lane = t & 63;
    const int mrow = lane & 15, quad = lane >> 4;
    const int wr = w & 1, wc = w >> 1;
    const int s0 = blockIdx.y*32 + wr*16;    // row within L
    const int n0 = blockIdx.x*128;           // block col base (128 cols)
    const int nc = n0 + wc*64;               // wave col base
    const int z = blockIdx.z;                // batch
    const int f = *fl;
    for (int e = t; e < 2048; e += 256) wl[e>>6][e&63] = ldsel(qk_w, woff + e, f);
    if (t < 64) bl2[t] = ldsel(qk_b, boff + t, f);

    const short* Bhp = Bh + (long)z*DIM_*L_;
    const short* Bmp = Bm + (long)z*DIM_*L_;
    const short* Blp = Bl + (long)z*DIM_*L_;
    f32x4 acc[4];
    #pragma unroll
    for (int i = 0; i < 4; i++) acc[i] = (f32x4){0.f,0.f,0.f,0.f};

    const long aoff0 = (long)(s0 + mrow)*L_ + quad*8;
    const long b0    = (long)(nc + mrow)*L_ + quad*8;
    const long bstp  = (long)16*L_;

    bf16x8 ahA, amA, alA, bhA[4], bmA[4], blA[4];
    ahA = *(const bf16x8*)(Ah + aoff0);
    amA = *(const bf16x8*)(Am + aoff0);
    alA = *(const bf16x8*)(Al + aoff0);
    #pragma unroll
    for (int nt = 0; nt < 4; nt++){
        long bo = b0 + nt*bstp;
        bhA[nt] = *(const bf16x8*)(Bhp + bo);
        bmA[nt] = *(const bf16x8*)(Bmp + bo);
        blA[nt] = *(const bf16x8*)(Blp + bo);
    }
    for (int k0 = 0; k0 < L_; k0 += 64){
        bf16x8 ahB, amB, alB, bhB[4], bmB[4], blB[4];
        {
            long an = aoff0 + k0 + 32;
            ahB = *(const bf16x8*)(Ah + an);
            amB = *(const bf16x8*)(Am + an);
            alB = *(const bf16x8*)(Al + an);
            #pragma unroll
            for (int nt = 0; nt < 4; nt++){
                long bo = b0 + nt*bstp + k0 + 32;
                bhB[nt] = *(const bf16x8*)(Bhp + bo);
                bmB[nt] = *(const bf16x8*)(Bmp + bo);
                blB[nt] = *(const bf16x8*)(Blp + bo);
            }
        }
        #pragma unroll
        for (int nt = 0; nt < 4; nt++){
            acc[nt] = MFMA(alA, bhA[nt], acc[nt]);
            acc[nt] = MFMA(amA, bmA[nt], acc[nt]);
            acc[nt] = MFMA(ahA, blA[nt], acc[nt]);
            acc[nt] = MFMA(amA, bhA[nt], acc[nt]);
            acc[nt] = MFMA(ahA, bmA[nt], acc[nt]);
            acc[nt] = MFMA(ahA, bhA[nt], acc[nt]);
        }
        if (k0 + 64 < L_){
            long an = aoff0 + k0 + 64;
            ahA = *(const bf16x8*)(Ah + an);
            amA = *(const bf16x8*)(Am + an);
            alA = *(const bf16x8*)(Al + an);
            #pragma unroll
            for (int nt = 0; nt < 4; nt++){
                long bo = b0 + nt*bstp + k0 + 64;
                bhA[nt] = *(const bf16x8*)(Bhp + bo);
                bmA[nt] = *(const bf16x8*)(Bmp + bo);
                blA[nt] = *(const bf16x8*)(Blp + bo);
            }
        }
        #pragma unroll
        for (int nt = 0; nt < 4; nt++){
            acc[nt] = MFMA(alB, bhB[nt], acc[nt]);
            acc[nt] = MFMA(amB, bmB[nt], acc[nt]);
            acc[nt] = MFMA(ahB, blB[nt], acc[nt]);
            acc[nt] = MFMA(amB, bhB[nt], acc[nt]);
            acc[nt] = MFMA(ahB, bmB[nt], acc[nt]);
            acc[nt] = MFMA(ahB, bhB[nt], acc[nt]);
        }
    }
    // m tile (with residual) -> LDS
    #pragma unroll
    for (int nt = 0; nt < 4; nt++)
    #pragma unroll
    for (int r = 0; r < 4; r++){
        long row = s0 + quad*4 + r;
        int col = nc + nt*16 + mrow;
        m_lds[wr*16 + quad*4 + r][wc*64 + nt*16 + mrow] =
            acc[nt][r] + xn[((long)(z*L_) + row)*DIM_ + col];
    }
    __syncthreads();
    // qk epilogue: wave w -> head (n0>>5)+w; out col j = lane; 32 rows
    const int j = lane;
    float wreg[32];
    #pragma unroll
    for (int d = 0; d < 32; d++) wreg[d] = wl[d][j];
    const float bj = bl2[j];
    const int hgl = (n0 >> 5) + w;           // global head
    #pragma unroll
    for (int rr = 0; rr < 32; rr++){
        const float* mp = &m_lds[rr][w*32];
        float a = bj;
        #pragma unroll
        for (int d = 0; d < 32; d += 4){
            f32x4 m4 = *(const f32x4*)(mp + d);
            a += m4[0]*wreg[d] + m4[1]*wreg[d+1] + m4[2]*wreg[d+2] + m4[3]*wreg[d+3];
        }
        a = fmaxf(a, 0.f);
        long rg = ((long)(z*HEADS_ + hgl))*L_ + blockIdx.y*32 + rr;
        if (q2h){
            short hh2, mm2; split2(a, hh2, mm2);
            if (j < 32){ q2h[rg*DH_+j]=hh2; q2m[rg*DH_+j]=mm2; }
            else { int d2 = j-32; k2h[rg*DH_+d2]=hh2; k2m[rg*DH_+d2]=mm2; }
        } else {
            short hh2, mm2, ll2; split3(a, hh2, mm2, ll2);
            if (j < 32){ qh[rg*DH_+j]=hh2; qm[rg*DH_+j]=mm2; ql[rg*DH_+j]=ll2; }
            else { int d2 = j-32; kh[rg*DH_+d2]=hh2; km[rg*DH_+d2]=mm2; kl[rg*DH_+d2]=ll2; }
        }
    }
}

// ---------------------------------------------------------------------------
// MFMA attention with fused v-projection epilogue (non-last layers).
// Direct blockIdx mapping (R10-measured best).  K-fragment register prefetch;
// PV xT loads hoisted above softmax.
// Non-last: q/k 3-term, 6-product scores, online pass, fused v2.
// Last: q/k 2-term from d_ws; 3-product scores; online pass then recompute
// pass with 2-DEEP ping-pong prefetch (4 loads in flight; tiny loop body
// cannot hide ~500cy latency with 1-ahead).  Identical load+MFMA sequence
// both passes -> scores bitwise-identical.
// Defer-max online softmax (THR=32 raw -> p <= e^1; 1/lsum cancels exactly).
// ---------------------------------------------------------------------------
__global__ __launch_bounds__(256)
void attn_mfma_kernel(const short* __restrict__ qh3, const short* __restrict__ qm3,
                      const short* __restrict__ ql3,
                      const short* __restrict__ kh3, const short* __restrict__ km3,
                      const short* __restrict__ kl3,
                      const short* __restrict__ q2h, const short* __restrict__ q2m,
                      const short* __restrict__ k2h, const short* __restrict__ k2m,
                      const short* __restrict__ xTh, const short* __restrict__ xTm,
                      const float* __restrict__ xn, const int* __restrict__ fl,
                      const void* __restrict__ v_w, long vwoff,
                      const void* __restrict__ v_b, long vboff,
                      short* __restrict__ v2h, short* __restrict__ v2m,
                      short* __restrict__ v2l,
                      float* __restrict__ attn_out)
{
    __shared__ float pt[4][16][37];
    __shared__ float mv_lds[64][36];
    __shared__ float wv[32][33];
    __shared__ float vb[32];
    const int t = threadIdx.x;
    const int w = t >> 6, lane = t & 63;
    const int mrow = lane & 15, quad = lane >> 4;
    const int bh = blockIdx.y, b = bh >> 3, h = bh & 7;
    const int s0 = blockIdx.x*64 + w*16;
    const bool last = (attn_out != nullptr);
    const float inv32 = 1.0f/32.0f;
    const long kb = (long)bh*L_*DH_;

    if (!last){
        const int f = *fl;
        for (int e = t; e < 1024; e += 256) wv[e>>5][e&31] = ldsel(v_w, vwoff + e, f);
        if (t < 32) vb[t] = ldsel(v_b, vboff + t, f);
    }

    bf16x8 a_h, a_m, a_l;
    {
        long qoff = ((long)bh*L_ + s0 + mrow)*DH_ + quad*8;
        if (last){
            a_h = *(const bf16x8*)(q2h + qoff);
            a_m = *(const bf16x8*)(q2m + qoff);
        } else {
            a_h = *(const bf16x8*)(qh3 + qoff);
            a_m = *(const bf16x8*)(qm3 + qoff);
            a_l = *(const bf16x8*)(ql3 + qoff);
        }
    }

    float m_run[4] = {-INFINITY,-INFINITY,-INFINITY,-INFINITY};
    float lsum[4] = {0.f,0.f,0.f,0.f};
    f32x4 pv[2];
    pv[0] = (f32x4){0.f,0.f,0.f,0.f};
    pv[1] = (f32x4){0.f,0.f,0.f,0.f};

    // preload pr=0 K-fragments
    bf16x8 kAh[2], kAm[2], kAl[2];
    #pragma unroll
    for (int u = 0; u < 2; u++){
        long koff = kb + (long)(u*16 + mrow)*DH_ + quad*8;
        if (last){
            kAh[u] = *(const bf16x8*)(k2h + koff);
            kAm[u] = *(const bf16x8*)(k2m + koff);
        } else {
            kAh[u] = *(const bf16x8*)(kh3 + koff);
            kAm[u] = *(const bf16x8*)(km3 + koff);
            kAl[u] = *(const bf16x8*)(kl3 + koff);
        }
    }

    for (int pr = 0; pr < 32; pr++){
        // prefetch next pr's K-fragments (in flight across MFMA + softmax)
        bf16x8 kBh[2], kBm[2], kBl[2];
        if (pr < 31){
            #pragma unroll
            for (int u = 0; u < 2; u++){
                long koff = kb + (long)(((pr+1)*2+u)*16 + mrow)*DH_ + quad*8;
                if (last){
                    kBh[u] = *(const bf16x8*)(k2h + koff);
                    kBm[u] = *(const bf16x8*)(k2m + koff);
                } else {
                    kBh[u] = *(const bf16x8*)(kh3 + koff);
                    kBm[u] = *(const bf16x8*)(km3 + koff);
                    kBl[u] = *(const bf16x8*)(kl3 + koff);
                }
            }
        }
        // PV xT loads hoisted above softmax (independent of it)
        bf16x8 xh8[2], xl8[2];
        if (!last){
            int j0 = pr*32;
            #pragma unroll
            for (int nt = 0; nt < 2; nt++){
                long xoff = ((long)(b*DIM_) + h*DH_ + nt*16 + mrow)*L_ + j0 + quad*8;
                xh8[nt] = *(const bf16x8*)(xTh + xoff);
                xl8[nt] = *(const bf16x8*)(xTm + xoff);
            }
        }
        f32x4 acc[2];
        #pragma unroll
        for (int u = 0; u < 2; u++){
            f32x4 a1 = (f32x4){0.f,0.f,0.f,0.f};
            f32x4 a2 = (f32x4){0.f,0.f,0.f,0.f};
            if (last){
                a1 = MFMA(a_m, kAh[u], a1);
                a1 = MFMA(a_h, kAm[u], a1);
                a2 = MFMA(a_h, kAh[u], a2);
            } else {
                a1 = MFMA(a_l, kAh[u], a1);
                a1 = MFMA(a_m, kAm[u], a1);
                a1 = MFMA(a_h, kAl[u], a1);
                a2 = MFMA(a_m, kAh[u], a2);
                a2 = MFMA(a_h, kAm[u], a2);
                a2 = MFMA(a_h, kAh[u], a2);
            }
            acc[u] = a1 + a2;
        }
        float tmv[4];
        #pragma unroll
        for (int r = 0; r < 4; r++){
            float tm = fmaxf(acc[0][r], acc[1][r]);
            tm = fmaxf(tm, __shfl_xor(tm, 1, 64));
            tm = fmaxf(tm, __shfl_xor(tm, 2, 64));
            tm = fmaxf(tm, __shfl_xor(tm, 4, 64));
            tm = fmaxf(tm, __shfl_xor(tm, 8, 64));
            tmv[r] = tm;
        }
        bool need = (tmv[0] > m_run[0] + 32.f) | (tmv[1] > m_run[1] + 32.f)
                  | (tmv[2] > m_run[2] + 32.f) | (tmv[3] > m_run[3] + 32.f);
        if (__ballot(need)){
            #pragma unroll
            for (int r = 0; r < 4; r++){
                float mnew = fmaxf(m_run[r], tmv[r]);
                float sc = __expf((m_run[r] - mnew) * inv32);
                lsum[r] *= sc; pv[0][r] *= sc; pv[1][r] *= sc;
                m_run[r] = mnew;
            }
        }
        #pragma unroll
        for (int r = 0; r < 4; r++){
            float p0 = __expf((acc[0][r] - m_run[r]) * inv32);
            float p1 = __expf((acc[1][r] - m_run[r]) * inv32);
            lsum[r] += p0 + p1;
            if (!last){
                pt[w][quad*4 + r][mrow]      = p0;
                pt[w][quad*4 + r][16 + mrow] = p1;
            }
        }
        if (!last){
            // per-wave LDS tile: same-wave write->read is in-order (lgkmcnt)
            const float* pp = &pt[w][mrow][quad*8];
            bf16x8 phi, plo;
            #pragma unroll
            for (int jj = 0; jj < 8; jj++){
                short hh, ll; split2(pp[jj], hh, ll);
                phi[jj] = hh; plo[jj] = ll;
            }
            #pragma unroll
            for (int nt = 0; nt < 2; nt++){
                pv[nt] = MFMA(plo, xh8[nt], pv[nt]);
                pv[nt] = MFMA(phi, xl8[nt], pv[nt]);
                pv[nt] = MFMA(phi, xh8[nt], pv[nt]);
            }
        }
        if (pr < 31){
            #pragma unroll
            for (int u = 0; u < 2; u++){
                kAh[u] = kBh[u]; kAm[u] = kBm[u];
                if (!last) kAl[u] = kBl[u];
            }
        }
    }
    #pragma unroll
    for (int r = 0; r < 4; r++){
        lsum[r] += __shfl_xor(lsum[r], 1, 64);
        lsum[r] += __shfl_xor(lsum[r], 2, 64);
        lsum[r] += __shfl_xor(lsum[r], 4, 64);
        lsum[r] += __shfl_xor(lsum[r], 8, 64);
    }
    float linv[4];
    #pragma unroll
    for (int r = 0; r < 4; r++) linv[r] = 1.0f / lsum[r];

    if (!last){
        // mv (= PV/l + resid) -> LDS
        #pragma unroll
        for (int nt = 0; nt < 2; nt++)
        #pragma unroll
        for (int r = 0; r < 4; r++){
            int lrow = w*16 + quad*4 + r;
            long row = s0 + quad*4 + r;
            float resid = xn[((long)(b*L_) + row)*DIM_ + h*DH_ + nt*16 + mrow];
            mv_lds[lrow][nt*16 + mrow] = pv[nt][r]*linv[r] + resid;
        }
        __syncthreads();
        // v2 = gelu(relu(mv @ v_w + v_b)); out col j, 2 half-row groups
        const int j = lane & 31, rh = lane >> 5;
        float wreg[32];
        #pragma unroll
        for (int d = 0; d < 32; d++) wreg[d] = wv[d][j];
        const float vbj = vb[j];
        #pragma unroll
        for (int rr = 0; rr < 8; rr++){
            int lrow = w*16 + rh*8 + rr;
            const float* mp = &mv_lds[lrow][0];
            float a = vbj;
            #pragma unroll
            for (int d = 0; d < 32; d += 4){
                f32x4 m4 = *(const f32x4*)(mp + d);
                a += m4[0]*wreg[d] + m4[1]*wreg[d+1] + m4[2]*wreg[d+2] + m4[3]*wreg[d+3];
            }
            a = geluf(fmaxf(a, 0.f));
            int l = blockIdx.x*64 + lrow;
            long idx = ((long)(b*L_) + l)*DIM_ + h*DH_ + j;
            short hh2, mm2, ll2; split3(a, hh2, mm2, ll2);
            v2h[idx] = hh2; v2m[idx] = mm2; v2l[idx] = ll2;
        }
    } else {
        // recompute pass: unroll x2 with named regs -> 2 tiles (4 loads) in
        // flight; same loads & MFMA order as before (bitwise-identical).
        long koff0 = kb + (long)mrow*DH_ + quad*8;
        bf16x8 h0 = *(const bf16x8*)(k2h + koff0);
        bf16x8 m0 = *(const bf16x8*)(k2m + koff0);
        bf16x8 h1 = *(const bf16x8*)(k2h + koff0 + 16*DH_);
        bf16x8 m1 = *(const bf16x8*)(k2m + koff0 + 16*DH_);
        for (int ct = 0; ct < 64; ct += 2){
            bf16x8 h2, m2, h3, m3;
            if (ct + 2 < 64){
                long ko2 = kb + (long)((ct+2)*16 + mrow)*DH_ + quad*8;
                h2 = *(const bf16x8*)(k2h + ko2);
                m2 = *(const bf16x8*)(k2m + ko2);
                h3 = *(const bf16x8*)(k2h + ko2 + 16*DH_);
                m3 = *(const bf16x8*)(k2m + ko2 + 16*DH_);
            }
            {
                f32x4 a1 = (f32x4){0.f,0.f,0.f,0.f};
                f32x4 a2 = (f32x4){0.f,0.f,0.f,0.f};
                a1 = MFMA(a_m, h0, a1);
                a1 = MFMA(a_h, m0, a1);
                a2 = MFMA(a_h, h0, a2);
                f32x4 a = a1 + a2;
                #pragma unroll
                for (int r = 0; r < 4; r++){
                    float pn = __expf((a[r] - m_run[r]) * inv32) * linv[r];
                    attn_out[((long)bh*L_ + s0 + quad*4 + r)*L_ + ct*16 + mrow] = pn;
                }
            }
            {
                f32x4 a1 = (f32x4){0.f,0.f,0.f,0.f};
                f32x4 a2 = (f32x4){0.f,0.f,0.f,0.f};
                a1 = MFMA(a_m, h1, a1);
                a1 = MFMA(a_h, m1, a1);
                a2 = MFMA(a_h, h1, a2);
                f32x4 a = a1 + a2;
                #pragma unroll
                for (int r = 0; r < 4; r++){
                    float pn = __expf((a[r] - m_run[r]) * inv32) * linv[r];
                    attn_out[((long)bh*L_ + s0 + quad*4 + r)*L_ + (ct+1)*16 + mrow] = pn;
                }
            }
            if (ct + 2 < 64){ h0 = h2; m0 = m2; h1 = h3; m1 = m3; }
        }
    }
}

extern "C" void kernel_launch(void* const* d_in, const int* in_sizes, int n_in,
                              void* d_out, int out_size, void* d_ws, size_t ws_size,
                              hipStream_t stream)
{
    const int o = (n_in >= 16) ? 3 : 2;
    const void* img    = d_in[0];
    const void* adj    = d_in[1];
    const void* conv_w = d_in[o+0];
    const void* conv_b = d_in[o+1];
    const void* bn_g   = d_in[o+2];
    const void* bn_b   = d_in[o+3];
    const void* emb_w  = d_in[o+4];
    const void* emb_b  = d_in[o+5];
    const void* ln_g   = d_in[o+6];
    const void* ln_b   = d_in[o+7];
    const void* qk_w   = d_in[o+8];
    const void* qk_b   = d_in[o+9];
    const void* v_w    = d_in[o+10];
    const void* v_b    = d_in[o+11];
    const void* proj_w = d_in[o+12];
    float* attn_out = (float*)d_out;   // reference output dtype = float32

    // d_out scratch (64M floats). Lifetimes: pre-loop {x0,psum,embT,pT},
    // loop {xn,xT,q3,k3,v2}; pT persists through the loop (read-only).
    // INVARIANT: final attn writes ALL of d_out and reads ONLY d_ws (q2/k2).
    float* S = (float*)d_out;
    const long M1 = 1L << 20;
    float* x     = S;                      // 0..2M (permanent)
    float* xn    = S + 2*M1;               // 2..4M (loop)
    short* sp    = (short*)(S + 6*M1);     // permanent shorts: adj splits, embT
    short* adjh  = sp;
    short* adjm  = sp + 1*M1;
    short* adjl  = sp + 2*M1;
    short* embTh = sp + 3*M1;              // 256K each (pre-loop)
    short* embTm = embTh + 262144;
    short* embTl = embTm + 262144;
    short* lp    = (short*)(S + 8*M1);     // loop shorts pool (floats 8..20.3M)
    short* xTh   = lp;                     // 2M shorts each
    short* xTm   = lp + 2*M1;
    short* xTl   = lp + 4*M1;
    short* qh3   = lp + 6*M1;
    short* qm3   = lp + 8*M1;
    short* ql3   = lp + 10*M1;
    short* kh3   = lp + 12*M1;
    short* km3   = lp + 14*M1;
    short* kl3   = lp + 16*M1;
    short* v2h   = lp + 18*M1;
    short* v2m   = lp + 20*M1;
    short* v2l   = lp + 22*M1;
    short* pTh   = lp + 24*M1;             // 64K x 3 layers each (pre-computed)
    short* pTm   = pTh + 3*65536;
    short* pTl   = pTm + 3*65536;
    float* psum  = S + 24*M1;              // pre-loop only (past loop pool+pT)
    float* psq   = psum + (long)EC_*NPATCH;
    short* x0h   = (short*)(S + 41*M1);    // 8M shorts each -> floats 41..53M
    short* x0m   = x0h + 8*M1;
    short* x0l   = x0m + 8*M1;

    float* wsf   = (float*)d_ws;           // ws use: 16 MB + 1 KB (proven size)
    int*   flag  = (int*)wsf;
    float* scaleA= wsf + 64;
    float* biasA = wsf + 128;
    short* q2h   = (short*)(wsf + 256);    // 2M shorts (4 MB) each: last-layer
    short* q2m   = q2h + 2*M1;             // q/k 2-term splits (16 MB total)
    short* k2h   = q2m + 2*M1;
    short* k2m   = k2h + 2*M1;

    detect_kernel<<<1, 64, 0, stream>>>(img, flag);
    split_adj_kernel<<<L_*L_/256, 256, 0, stream>>>(flag, adj, adjh, adjm, adjl);
    tsplit_kernel<<<dim3(4,16,1), 256, 0, stream>>>(flag, emb_w, 0, 0, PD_, DIM_,
                                                    embTh, embTm, embTl, 0);
    // all 3 layers' proj_w transposed splits in one dispatch (z = layer)
    tsplit_kernel<<<dim3(4,4,3), 256, 0, stream>>>(flag, proj_w, 0, (long)DIM_*DIM_,
                                                   DIM_, DIM_, pTh, pTm, pTl, 65536);
    conv_stats_kernel<<<NPATCH, 256, 0, stream>>>(flag, img, conv_w, conv_b, psum, psq);
    bn_stats_kernel<<<EC_, 256, 0, stream>>>(flag, psum, psq, bn_g, bn_b, scaleA, biasA);
    bn_gelu_pool_kernel<<<NPATCH, 256, 0, stream>>>(flag, img, conv_w, conv_b,
                                                    scaleA, biasA, x0h, x0m, x0l);

    // x = x0 @ emb_w + emb_b   (8192x1024 @ 1024x256) via MFMA splits
    mfma_gemm<<<dim3(2,256,1), 256, 0, stream>>>(
        x0h, x0m, x0l, 0,  embTh, embTm, embTl, 0,
        emb_b, 0, flag,  nullptr, 0,  x, 0,  DIM_, PD_);

    for (int i = 0; i < DEPTH_; i++){
        const bool last = (i == DEPTH_-1);
        ln_repack_kernel<<<NROWS/32/8, 256, 0, stream>>>(flag, x,
            ln_g, (long)i*DIM_, ln_b, (long)i*DIM_, xn, xTh, xTm, xTl);
        // m = A @ xn + xn (LDS-resident) -> qk = relu(m @ qk_w + qk_b)
        gemm_axn_qk<<<dim3(2,32,8), 256, 0, stream>>>(
            adjh, adjm, adjl,  xTh, xTm, xTl,  xn, flag,
            qk_w, (long)i*DH_*2*DH_, qk_b, (long)i*2*DH_,
            qh3, qm3, ql3, kh3, km3, kl3,
            last ? q2h : nullptr, last ? q2m : nullptr,
            last ? k2h : nullptr, last ? k2m : nullptr);
        attn_mfma_kernel<<<dim3(16, B_*HEADS_), 256, 0, stream>>>(
            qh3, qm3, ql3, kh3, km3, kl3, q2h, q2m, k2h, k2m,
            xTh, xTm, xn, flag,
            v_w, (long)i*DH_*DH_, v_b, (long)i*DH_,
            v2h, v2m, v2l,
            last ? attn_out : nullptr);
        if (!last){
            // x = v2 @ proj_w + xn  (pT pre-computed for this layer)
            mfma_gemm<<<dim3(2,256,1), 256, 0, stream>>>(
                v2h, v2m, v2l, 0,
                pTh + (long)i*65536, pTm + (long)i*65536, pTl + (long)i*65536, 0,
                nullptr, 0, flag,  xn, 0,  x, 0,  DIM_, DIM_);
        }
    }
}

// Round 13
// 1621.644 us; speedup vs baseline: 1.0727x; 1.0727x over previous
//
#include <hip/hip_runtime.h>
#include <hip/hip_bf16.h>
#include <math.h>

typedef __hip_bfloat16 bf16;
typedef __attribute__((ext_vector_type(8))) short bf16x8;
typedef __attribute__((ext_vector_type(4))) float f32x4;

#define MFMA(a,b,c) __builtin_amdgcn_mfma_f32_16x16x32_bf16(a,b,c,0,0,0)

#define B_ 8
#define C_ 3
#define IMG_ 512
#define P_ 16
#define DIM_ 256
#define HEADS_ 8
#define DEPTH_ 4
#define DH_ 32
#define L_ 1024
#define EC_ 64
#define PD_ 1024
#define NPATCH 8192
#define NROWS 65536

__device__ __forceinline__ float ldsel(const void* p, long i, int m){
    return m ? __bfloat162float(((const bf16*)p)[i]) : ((const float*)p)[i];
}
__device__ __forceinline__ float geluf(float x){
    return 0.5f * x * (1.0f + erff(x * 0.70710678118654752f));
}
__device__ __forceinline__ short f2bf_s(float f){
    bf16 h = __float2bfloat16(f); return *(short*)&h;
}
__device__ __forceinline__ float bfs2f(short s){
    bf16 h = *(bf16*)&s; return __bfloat162float(h);
}
__device__ __forceinline__ void split2(float f, short& hi, short& lo){
    hi = f2bf_s(f);
    lo = f2bf_s(f - bfs2f(hi));
}
__device__ __forceinline__ void split3(float f, short& h, short& m, short& l){
    h = f2bf_s(f); float r1 = f - bfs2f(h);
    m = f2bf_s(r1); float r2 = r1 - bfs2f(m);
    l = f2bf_s(r2);
}

// Runtime input-dtype detection (bf16 vs fp32): exponent-byte histogram.
__global__ void detect_kernel(const void* __restrict__ img, int* __restrict__ flag)
{
    const unsigned* w = (const unsigned*)img;
    const int t = threadIdx.x;
    int c = 0;
    #pragma unroll
    for (int i = 0; i < 4; i++){
        unsigned b = (w[t*4 + i] >> 7) & 0xFFu;
        if (b >= 100u && b <= 145u) c++;
    }
    #pragma unroll
    for (int o = 32; o > 0; o >>= 1) c += __shfl_xor(c, o, 64);
    if (t == 0) *flag = (c > 180) ? 1 : 0;
}

// ---------------------------------------------------------------------------
// Conv stats pass: lane = output channel (broadcast inp reads, conflict-free),
// zero-padded 18x18 tile (branch-free, bitwise-identical conv values).
// ---------------------------------------------------------------------------
__global__ void conv_stats_kernel(const int* __restrict__ fl,
                                  const void* __restrict__ img,
                                  const void* __restrict__ conv_w,
                                  const void* __restrict__ conv_b,
                                  float* __restrict__ psum, float* __restrict__ psq)
{
    const int f = *fl;
    __shared__ float inp[3*18*18];
    __shared__ float wl[EC_*27];
    __shared__ float reds[4][64], redq[4][64];
    const int n = blockIdx.x, t = threadIdx.x;
    const int b = n >> 10, l = n & 1023;
    const int gy = l >> 5, gx = l & 31;
    const int w = t >> 6, o = t & 63;
    for (int e = t; e < EC_*27; e += 256) wl[e] = ldsel(conv_w, e, f);
    for (int e = t; e < 3*18*18; e += 256){
        int c = e / 324, rem = e - c*324;
        int y = rem / 18, x = rem - y*18;
        float v = 0.f;
        if (y >= 1 && y <= 16 && x >= 1 && x <= 16)
            v = ldsel(img, ((long)(b*C_+c)*IMG_ + gy*P_ + (y-1))*IMG_ + gx*P_ + (x-1), f);
        inp[e] = v;
    }
    __syncthreads();
    float wr[27];
    #pragma unroll
    for (int i = 0; i < 27; i++) wr[i] = wl[o*27 + i];
    const float cb = ldsel(conv_b, o, f);
    float s = 0.f, sq = 0.f;
    #pragma unroll
    for (int i = 0; i < 16; i++){
        int pix = w*16 + i;
        int oy = pix >> 3, ox = pix & 7;
        float acc = cb;
        #pragma unroll
        for (int c = 0; c < 3; c++)
        #pragma unroll
        for (int ky = 0; ky < 3; ky++)
        #pragma unroll
        for (int kx = 0; kx < 3; kx++)
            acc += inp[c*324 + (2*oy+ky)*18 + 2*ox+kx] * wr[c*9+ky*3+kx];
        s += acc; sq += acc*acc;
    }
    reds[w][o] = s; redq[w][o] = sq;
    __syncthreads();
    if (t < 64){
        float S = reds[0][t]+reds[1][t]+reds[2][t]+reds[3][t];
        float Q = redq[0][t]+redq[1][t]+redq[2][t]+redq[3][t];
        psum[(long)t*NPATCH + n] = S;
        psq [(long)t*NPATCH + n] = Q;
    }
}

__global__ void bn_stats_kernel(const int* __restrict__ fl,
                                const float* __restrict__ psum, const float* __restrict__ psq,
                                const void* __restrict__ bn_g, const void* __restrict__ bn_b,
                                float* __restrict__ scaleA, float* __restrict__ biasA)
{
    const int f = *fl;
    __shared__ float rs[256], rq[256];
    const int o = blockIdx.x, t = threadIdx.x;
    float S = 0.f, Q = 0.f;
    for (int n = t; n < NPATCH; n += 256){ S += psum[(long)o*NPATCH+n]; Q += psq[(long)o*NPATCH+n]; }
    rs[t] = S; rq[t] = Q; __syncthreads();
    for (int st = 128; st > 0; st >>= 1){
        if (t < st){ rs[t] += rs[t+st]; rq[t] += rq[t+st]; }
        __syncthreads();
    }
    if (t == 0){
        const float Ninv = 1.0f / (float)((long)NPATCH * 64);
        float mean = rs[0] * Ninv;
        float var  = rq[0] * Ninv - mean*mean;
        float rstd = rsqrtf(var + 1e-5f);
        float sc = ldsel(bn_g, o, f) * rstd;
        scaleA[o] = sc;
        biasA[o]  = ldsel(bn_b, o, f) - mean*sc;
    }
}

// Recompute conv (bitwise-identical), BN + exact GELU + maxpool; emits x0 splits.
__global__ void bn_gelu_pool_kernel(const int* __restrict__ fl,
                                    const void* __restrict__ img,
                                    const void* __restrict__ conv_w,
                                    const void* __restrict__ conv_b,
                                    const float* __restrict__ scaleA,
                                    const float* __restrict__ biasA,
                                    short* __restrict__ x0h, short* __restrict__ x0m,
                                    short* __restrict__ x0l)
{
    const int f = *fl;
    __shared__ float inp[3*18*18];
    __shared__ float wl[EC_*27];
    __shared__ float cosb[64][65];
    __shared__ float poolb[64*17];
    __shared__ float sA[64], bA[64];
    const int n = blockIdx.x, t = threadIdx.x;
    const int b = n >> 10, l = n & 1023;
    const int gy = l >> 5, gx = l & 31;
    const int w = t >> 6, o = t & 63;
    for (int e = t; e < EC_*27; e += 256) wl[e] = ldsel(conv_w, e, f);
    for (int e = t; e < 3*18*18; e += 256){
        int c = e / 324, rem = e - c*324;
        int y = rem / 18, x = rem - y*18;
        float v = 0.f;
        if (y >= 1 && y <= 16 && x >= 1 && x <= 16)
            v = ldsel(img, ((long)(b*C_+c)*IMG_ + gy*P_ + (y-1))*IMG_ + gx*P_ + (x-1), f);
        inp[e] = v;
    }
    if (t < 64){ sA[t] = scaleA[t]; bA[t] = biasA[t]; }
    __syncthreads();
    float wr[27];
    #pragma unroll
    for (int i = 0; i < 27; i++) wr[i] = wl[o*27 + i];
    const float cb = ldsel(conv_b, o, f);
    const float sc = sA[o], bb = bA[o];
    #pragma unroll
    for (int i = 0; i < 16; i++){
        int pix = w*16 + i;
        int oy = pix >> 3, ox = pix & 7;
        float acc = cb;
        #pragma unroll
        for (int c = 0; c < 3; c++)
        #pragma unroll
        for (int ky = 0; ky < 3; ky++)
        #pragma unroll
        for (int kx = 0; kx < 3; kx++)
            acc += inp[c*324 + (2*oy+ky)*18 + 2*ox+kx] * wr[c*9+ky*3+kx];
        cosb[pix][o] = geluf(acc*sc + bb);
    }
    __syncthreads();
    #pragma unroll
    for (int j = 0; j < 4; j++){
        int pp = w*4 + j;
        int py = pp >> 2, px = pp & 3;
        int y0 = max(0, 2*py-1), y1 = min(7, 2*py+1);
        int xs = max(0, 2*px-1), x1 = min(7, 2*px+1);
        float mx = -INFINITY;
        for (int y = y0; y <= y1; y++)
            for (int x = xs; x <= x1; x++)
                mx = fmaxf(mx, cosb[y*8+x][o]);
        poolb[o*17 + pp] = mx;
    }
    __syncthreads();
    for (int e = t; e < 1024; e += 256){
        float v = poolb[(e>>4)*17 + (e&15)];
        short h, m, lo; split3(v, h, m, lo);
        long idx = (long)n*PD_ + e;
        x0h[idx] = h; x0m[idx] = m; x0l[idx] = lo;
    }
}

// Elementwise 3-term split (adjacency).
__global__ void split_adj_kernel(const int* __restrict__ fl, const void* __restrict__ adj,
                                 short* __restrict__ Ah, short* __restrict__ Am,
                                 short* __restrict__ Al)
{
    const int f = *fl;
    long i = (long)blockIdx.x*256 + threadIdx.x;
    short h, m, l; split3(ldsel(adj, i, f), h, m, l);
    Ah[i] = h; Am[i] = m; Al[i] = l;
}

// Transpose + 3-term split: out[c][r] = src[r][c].  grid (C/64, R/64, Z).
__global__ void tsplit_kernel(const int* __restrict__ fl, const void* __restrict__ src,
                              long soff, long zsStride, int R, int Ccols,
                              short* __restrict__ oh, short* __restrict__ om,
                              short* __restrict__ ol, long ozStride)
{
    __shared__ float tile[64][65];
    const int f = *fl;
    const int t = threadIdx.x;
    const int zz = blockIdx.z;
    const long sb = soff + (long)zz*zsStride;
    oh += (long)zz*ozStride; om += (long)zz*ozStride; ol += (long)zz*ozStride;
    const int c0 = blockIdx.x*64, r0 = blockIdx.y*64;
    for (int e = t; e < 4096; e += 256){
        int r = e >> 6, c = e & 63;
        tile[r][c] = ldsel(src, sb + (long)(r0+r)*Ccols + c0+c, f);
    }
    __syncthreads();
    const int ch = t >> 2, lg = t & 3;
    long ob = (long)(c0+ch)*R + r0 + lg*16;
    bf16x8 h0,h1,m0,m1,l0,l1;
    #pragma unroll
    for (int i = 0; i < 8; i++){
        short h,m,l;
        split3(tile[lg*16+i][ch], h,m,l);    h0[i]=h; m0[i]=m; l0[i]=l;
        split3(tile[lg*16+8+i][ch], h,m,l);  h1[i]=h; m1[i]=m; l1[i]=l;
    }
    *(bf16x8*)(oh+ob) = h0; *(bf16x8*)(oh+ob+8) = h1;
    *(bf16x8*)(om+ob) = m0; *(bf16x8*)(om+ob+8) = m1;
    *(bf16x8*)(ol+ob) = l0; *(bf16x8*)(ol+ob+8) = l1;
}

// ---------------------------------------------------------------------------
// Fused LayerNorm + transpose-split: x (rows of 256) -> xn fp32 row-major AND
// xT (b,256,L) 3-term splits.  32 rows/block, 256 blocks.
// ---------------------------------------------------------------------------
__global__ void ln_repack_kernel(const int* __restrict__ fl,
                                 const float* __restrict__ x,
                                 const void* __restrict__ g, long goff,
                                 const void* __restrict__ beta, long boff,
                                 float* __restrict__ xn,
                                 short* __restrict__ xTh, short* __restrict__ xTm,
                                 short* __restrict__ xTl)
{
    __shared__ float tile[32][257];
    __shared__ float gs[256], bs[256];
    __shared__ float pm[8][32], pq[8][32];
    __shared__ float mean_s[32], rstd_s[32];
    const int f = *fl;
    const int t = threadIdx.x;
    const int r0 = blockIdx.x*32;            // global row (b*L + l)
    const int b = r0 >> 10, l0 = r0 & 1023;
    gs[t] = ldsel(g, goff + t, f);
    bs[t] = ldsel(beta, boff + t, f);
    for (int e = t; e < 32*256; e += 256){
        int r = e >> 8, c = e & 255;
        tile[r][c] = x[(long)(r0+r)*DIM_ + c];
    }
    __syncthreads();
    {
        int row = t & 31, part = t >> 5;
        float s = 0.f, q = 0.f;
        #pragma unroll
        for (int c = 0; c < 32; c++){
            float v = tile[row][part*32 + c];
            s += v; q += v*v;
        }
        pm[part][row] = s; pq[part][row] = q;
    }
    __syncthreads();
    if (t < 32){
        float S = 0.f, Q = 0.f;
        #pragma unroll
        for (int p2 = 0; p2 < 8; p2++){ S += pm[p2][t]; Q += pq[p2][t]; }
        float mean = S * (1.0f/256.0f);
        float var  = Q * (1.0f/256.0f) - mean*mean;
        mean_s[t] = mean;
        rstd_s[t] = rsqrtf(var + 1e-5f);
    }
    __syncthreads();
    for (int e = t; e < 32*256; e += 256){
        int r = e >> 8, c = e & 255;
        float v = (tile[r][c] - mean_s[r])*rstd_s[r]*gs[c] + bs[c];
        tile[r][c] = v;
        xn[(long)(r0+r)*DIM_ + c] = v;
    }
    __syncthreads();
    // transposed split emit: 2 passes of 128 cols; 2 lanes cover the 32 rows
    const int half = t & 1, cB = t >> 1;
    #pragma unroll
    for (int gp = 0; gp < 2; gp++){
        int c = gp*128 + cB;
        long ob = ((long)(b*DIM_) + c)*L_ + l0 + half*16;
        bf16x8 h0, m0, l0v;
        #pragma unroll
        for (int i = 0; i < 8; i++){
            short hh, mm, ll;
            split3(tile[half*16 + i][c], hh, mm, ll);
            h0[i]=hh; m0[i]=mm; l0v[i]=ll;
        }
        *(bf16x8*)(xTh+ob) = h0; *(bf16x8*)(xTm+ob) = m0; *(bf16x8*)(xTl+ob) = l0v;
        bf16x8 h1, m1, l1v;
        #pragma unroll
        for (int i = 0; i < 8; i++){
            short hh, mm, ll;
            split3(tile[half*16 + 8 + i][c], hh, mm, ll);
            h1[i]=hh; m1[i]=mm; l1v[i]=ll;
        }
        *(bf16x8*)(xTh+ob+8) = h1; *(bf16x8*)(xTm+ob+8) = m1; *(bf16x8*)(xTl+ob+8) = l1v;
    }
}

// ---------------------------------------------------------------------------
// Generic MFMA GEMM, fp32-accurate via 3-term bf16 splits (6 products).
// Tile 32 rows x 128 cols; 4 waves = 2 row-strips x 2 col-halves; acc[4].
// Register ping-pong double-buffer.  K % 64 == 0.  (R8/R10-measured best.)
// ---------------------------------------------------------------------------
__global__ __launch_bounds__(256)
void mfma_gemm(const short* __restrict__ Ah, const short* __restrict__ Am,
               const short* __restrict__ Al, long strAb,
               const short* __restrict__ Bh, const short* __restrict__ Bm,
               const short* __restrict__ Bl, long strBb,
               const void* __restrict__ bias, long biasOff, const int* __restrict__ fl,
               const float* __restrict__ Dadd, long strDb,
               float* __restrict__ C, long strCb,
               int N, int K)
{
    const int t = threadIdx.x;
    const int w = t >> 6, lane = t & 63;
    const int mrow = lane & 15, quad = lane >> 4;
    const int wr = w & 1, wc = w >> 1;
    const int s0 = blockIdx.y*32 + wr*16;
    const int n0 = blockIdx.x*128 + wc*64;
    const int z = blockIdx.z;
    const short* Ahp = Ah + (long)z*strAb;
    const short* Amp = Am + (long)z*strAb;
    const short* Alp = Al + (long)z*strAb;
    const short* Bhp = Bh + (long)z*strBb;
    const short* Bmp = Bm + (long)z*strBb;
    const short* Blp = Bl + (long)z*strBb;
    f32x4 acc[4];
    #pragma unroll
    for (int i = 0; i < 4; i++) acc[i] = (f32x4){0.f,0.f,0.f,0.f};

    const long aoff0 = (long)(s0 + mrow)*K + quad*8;
    const long b0    = (long)(n0 + mrow)*K + quad*8;
    const long bstp  = (long)16*K;

    bf16x8 ahA, amA, alA, bhA[4], bmA[4], blA[4];
    ahA = *(const bf16x8*)(Ahp + aoff0);
    amA = *(const bf16x8*)(Amp + aoff0);
    alA = *(const bf16x8*)(Alp + aoff0);
    #pragma unroll
    for (int nt = 0; nt < 4; nt++){
        long bo = b0 + nt*bstp;
        bhA[nt] = *(const bf16x8*)(Bhp + bo);
        bmA[nt] = *(const bf16x8*)(Bmp + bo);
        blA[nt] = *(const bf16x8*)(Blp + bo);
    }
    for (int k0 = 0; k0 < K; k0 += 64){
        bf16x8 ahB, amB, alB, bhB[4], bmB[4], blB[4];
        {
            long an = aoff0 + k0 + 32;
            ahB = *(const bf16x8*)(Ahp + an);
            amB = *(const bf16x8*)(Amp + an);
            alB = *(const bf16x8*)(Alp + an);
            #pragma unroll
            for (int nt = 0; nt < 4; nt++){
                long bo = b0 + nt*bstp + k0 + 32;
                bhB[nt] = *(const bf16x8*)(Bhp + bo);
                bmB[nt] = *(const bf16x8*)(Bmp + bo);
                blB[nt] = *(const bf16x8*)(Blp + bo);
            }
        }
        #pragma unroll
        for (int nt = 0; nt < 4; nt++){
            acc[nt] = MFMA(alA, bhA[nt], acc[nt]);
            acc[nt] = MFMA(amA, bmA[nt], acc[nt]);
            acc[nt] = MFMA(ahA, blA[nt], acc[nt]);
            acc[nt] = MFMA(amA, bhA[nt], acc[nt]);
            acc[nt] = MFMA(ahA, bmA[nt], acc[nt]);
            acc[nt] = MFMA(ahA, bhA[nt], acc[nt]);
        }
        if (k0 + 64 < K){
            long an = aoff0 + k0 + 64;
            ahA = *(const bf16x8*)(Ahp + an);
            amA = *(const bf16x8*)(Amp + an);
            alA = *(const bf16x8*)(Alp + an);
            #pragma unroll
            for (int nt = 0; nt < 4; nt++){
                long bo = b0 + nt*bstp + k0 + 64;
                bhA[nt] = *(const bf16x8*)(Bhp + bo);
                bmA[nt] = *(const bf16x8*)(Bmp + bo);
                blA[nt] = *(const bf16x8*)(Blp + bo);
            }
        }
        #pragma unroll
        for (int nt = 0; nt < 4; nt++){
            acc[nt] = MFMA(alB, bhB[nt], acc[nt]);
            acc[nt] = MFMA(amB, bmB[nt], acc[nt]);
            acc[nt] = MFMA(ahB, blB[nt], acc[nt]);
            acc[nt] = MFMA(amB, bhB[nt], acc[nt]);
            acc[nt] = MFMA(ahB, bmB[nt], acc[nt]);
            acc[nt] = MFMA(ahB, bhB[nt], acc[nt]);
        }
    }
    const int f = *fl;
    #pragma unroll
    for (int nt = 0; nt < 4; nt++)
    #pragma unroll
    for (int r = 0; r < 4; r++){
        long row = s0 + quad*4 + r;
        int col = n0 + nt*16 + mrow;
        float v = acc[nt][r];
        if (bias) v += ldsel(bias, biasOff + col, f);
        if (Dadd) v += Dadd[(long)z*strDb + row*N + col];
        C[(long)z*strCb + row*N + col] = v;
    }
}

// ---------------------------------------------------------------------------
// Fused A@xn GEMM + qk projection.  m = adj @ xn + xn stays in LDS.
// Tile 32 rows x 128 cols; 4 waves; register ping-pong double-buffer.
// grid (2, 32, 8) = 512 blocks, direct blockIdx mapping (R10-measured best).
// Non-last: emits q/k 3-term splits. Last: 2-term splits into d_ws
// (INVARIANT: last-layer attn reads only d_ws).
// ---------------------------------------------------------------------------
__global__ __launch_bounds__(256)
void gemm_axn_qk(const short* __restrict__ Ah, const short* __restrict__ Am,
                 const short* __restrict__ Al,
                 const short* __restrict__ Bh, const short* __restrict__ Bm,
                 const short* __restrict__ Bl,
                 const float* __restrict__ xn, const int* __restrict__ fl,
                 const void* __restrict__ qk_w, long woff,
                 const void* __restrict__ qk_b, long boff,
                 short* __restrict__ qh, short* __restrict__ qm, short* __restrict__ ql,
                 short* __restrict__ kh, short* __restrict__ km, short* __restrict__ kl,
                 short* __restrict__ q2h, short* __restrict__ q2m,
                 short* __restrict__ k2h, short* __restrict__ k2m)
{
    __shared__ float m_lds[32][132];
    __shared__ float wl[32][65];
    __shared__ float bl2[64];
    const int t = threadIdx.x;
    const int w = t >> 6, lane = t & 63;
    const int mrow = lane & 15, quad = lane >> 4;
    const int wr = w & 1, wc = w >> 1;
    const int s0 = blockIdx.y*32 + wr*16;    // row within L
    const int n0 = blockIdx.x*128;           // block col base (128 cols)
    const int nc = n0 + wc*64;               // wave col base
    const int z = blockIdx.z;                // batch
    const int f = *fl;
    for (int e = t; e < 2048; e += 256) wl[e>>6][e&63] = ldsel(qk_w, woff + e, f);
    if (t < 64) bl2[t] = ldsel(qk_b, boff + t, f);

    const short* Bhp = Bh + (long)z*DIM_*L_;
    const short* Bmp = Bm + (long)z*DIM_*L_;
    const short* Blp = Bl + (long)z*DIM_*L_;
    f32x4 acc[4];
    #pragma unroll
    for (int i = 0; i < 4; i++) acc[i] = (f32x4){0.f,0.f,0.f,0.f};

    const long aoff0 = (long)(s0 + mrow)*L_ + quad*8;
    const long b0    = (long)(nc + mrow)*L_ + quad*8;
    const long bstp  = (long)16*L_;

    bf16x8 ahA, amA, alA, bhA[4], bmA[4], blA[4];
    ahA = *(const bf16x8*)(Ah + aoff0);
    amA = *(const bf16x8*)(Am + aoff0);
    alA = *(const bf16x8*)(Al + aoff0);
    #pragma unroll
    for (int nt = 0; nt < 4; nt++){
        long bo = b0 + nt*bstp;
        bhA[nt] = *(const bf16x8*)(Bhp + bo);
        bmA[nt] = *(const bf16x8*)(Bmp + bo);
        blA[nt] = *(const bf16x8*)(Blp + bo);
    }
    for (int k0 = 0; k0 < L_; k0 += 64){
        bf16x8 ahB, amB, alB, bhB[4], bmB[4], blB[4];
        {
            long an = aoff0 + k0 + 32;
            ahB = *(const bf16x8*)(Ah + an);
            amB = *(const bf16x8*)(Am + an);
            alB = *(const bf16x8*)(Al + an);
            #pragma unroll
            for (int nt = 0; nt < 4; nt++){
                long bo = b0 + nt*bstp + k0 + 32;
                bhB[nt] = *(const bf16x8*)(Bhp + bo);
                bmB[nt] = *(const bf16x8*)(Bmp + bo);
                blB[nt] = *(const bf16x8*)(Blp + bo);
            }
        }
        #pragma unroll
        for (int nt = 0; nt < 4; nt++){
            acc[nt] = MFMA(alA, bhA[nt], acc[nt]);
            acc[nt] = MFMA(amA, bmA[nt], acc[nt]);
            acc[nt] = MFMA(ahA, blA[nt], acc[nt]);
            acc[nt] = MFMA(amA, bhA[nt], acc[nt]);
            acc[nt] = MFMA(ahA, bmA[nt], acc[nt]);
            acc[nt] = MFMA(ahA, bhA[nt], acc[nt]);
        }
        if (k0 + 64 < L_){
            long an = aoff0 + k0 + 64;
            ahA = *(const bf16x8*)(Ah + an);
            amA = *(const bf16x8*)(Am + an);
            alA = *(const bf16x8*)(Al + an);
            #pragma unroll
            for (int nt = 0; nt < 4; nt++){
                long bo = b0 + nt*bstp + k0 + 64;
                bhA[nt] = *(const bf16x8*)(Bhp + bo);
                bmA[nt] = *(const bf16x8*)(Bmp + bo);
                blA[nt] = *(const bf16x8*)(Blp + bo);
            }
        }
        #pragma unroll
        for (int nt = 0; nt < 4; nt++){
            acc[nt] = MFMA(alB, bhB[nt], acc[nt]);
            acc[nt] = MFMA(amB, bmB[nt], acc[nt]);
            acc[nt] = MFMA(ahB, blB[nt], acc[nt]);
            acc[nt] = MFMA(amB, bhB[nt], acc[nt]);
            acc[nt] = MFMA(ahB, bmB[nt], acc[nt]);
            acc[nt] = MFMA(ahB, bhB[nt], acc[nt]);
        }
    }
    // m tile (with residual) -> LDS
    #pragma unroll
    for (int nt = 0; nt < 4; nt++)
    #pragma unroll
    for (int r = 0; r < 4; r++){
        long row = s0 + quad*4 + r;
        int col = nc + nt*16 + mrow;
        m_lds[wr*16 + quad*4 + r][wc*64 + nt*16 + mrow] =
            acc[nt][r] + xn[((long)(z*L_) + row)*DIM_ + col];
    }
    __syncthreads();
    // qk epilogue: wave w -> head (n0>>5)+w; out col j = lane; 32 rows
    const int j = lane;
    float wreg[32];
    #pragma unroll
    for (int d = 0; d < 32; d++) wreg[d] = wl[d][j];
    const float bj = bl2[j];
    const int hgl = (n0 >> 5) + w;           // global head
    #pragma unroll
    for (int rr = 0; rr < 32; rr++){
        const float* mp = &m_lds[rr][w*32];
        float a = bj;
        #pragma unroll
        for (int d = 0; d < 32; d += 4){
            f32x4 m4 = *(const f32x4*)(mp + d);
            a += m4[0]*wreg[d] + m4[1]*wreg[d+1] + m4[2]*wreg[d+2] + m4[3]*wreg[d+3];
        }
        a = fmaxf(a, 0.f);
        long rg = ((long)(z*HEADS_ + hgl))*L_ + blockIdx.y*32 + rr;
        if (q2h){
            short hh2, mm2; split2(a, hh2, mm2);
            if (j < 32){ q2h[rg*DH_+j]=hh2; q2m[rg*DH_+j]=mm2; }
            else { int d2 = j-32; k2h[rg*DH_+d2]=hh2; k2m[rg*DH_+d2]=mm2; }
        } else {
            short hh2, mm2, ll2; split3(a, hh2, mm2, ll2);
            if (j < 32){ qh[rg*DH_+j]=hh2; qm[rg*DH_+j]=mm2; ql[rg*DH_+j]=ll2; }
            else { int d2 = j-32; kh[rg*DH_+d2]=hh2; km[rg*DH_+d2]=mm2; kl[rg*DH_+d2]=ll2; }
        }
    }
}

// ---------------------------------------------------------------------------
// MFMA attention, 2 q-fragments per wave (rows s0 and s0+64) sharing the
// K-fragment and xT loads: 36 MFMA per 10 load-packets (2x arithmetic
// intensity of the 1-frag version), and K-panel re-reads halve (8 blocks/bh).
// Per-16-row-group defer-max ballots kept SEPARATE per fragment -> rescale
// trajectories identical to the 1-frag version -> bitwise-identical outputs.
// grid (8, 64) = 512 blocks.
// Non-last: q/k 3-term, 6-product scores, online pass, fused v2 epilogue.
// Last: q/k 2-term from d_ws; 3-product scores; online pass then recompute
// pass (2-deep prefetch, K loads shared across both fragments).
// ---------------------------------------------------------------------------
__global__ __launch_bounds__(256)
void attn_mfma_kernel(const short* __restrict__ qh3, const short* __restrict__ qm3,
                      const short* __restrict__ ql3,
                      const short* __restrict__ kh3, const short* __restrict__ km3,
                      const short* __restrict__ kl3,
                      const short* __restrict__ q2h, const short* __restrict__ q2m,
                      const short* __restrict__ k2h, const short* __restrict__ k2m,
                      const short* __restrict__ xTh, const short* __restrict__ xTm,
                      const float* __restrict__ xn, const int* __restrict__ fl,
                      const void* __restrict__ v_w, long vwoff,
                      const void* __restrict__ v_b, long vboff,
                      short* __restrict__ v2h, short* __restrict__ v2m,
                      short* __restrict__ v2l,
                      float* __restrict__ attn_out)
{
    __shared__ float pt[4][32][37];
    __shared__ float mv_lds[128][36];
    __shared__ float wv[32][33];
    __shared__ float vb[32];
    const int t = threadIdx.x;
    const int w = t >> 6, lane = t & 63;
    const int mrow = lane & 15, quad = lane >> 4;
    const int bh = blockIdx.y, b = bh >> 3, h = bh & 7;
    const int s0 = blockIdx.x*128 + w*16;    // frag A rows; frag B = s0+64
    const bool last = (attn_out != nullptr);
    const float inv32 = 1.0f/32.0f;
    const long kb = (long)bh*L_*DH_;

    if (!last){
        const int f = *fl;
        for (int e = t; e < 1024; e += 256) wv[e>>5][e&31] = ldsel(v_w, vwoff + e, f);
        if (t < 32) vb[t] = ldsel(v_b, vboff + t, f);
    }

    bf16x8 qa_h, qa_m, qa_l, qb_h, qb_m, qb_l;
    {
        long qoffA = ((long)bh*L_ + s0 + mrow)*DH_ + quad*8;
        long qoffB = qoffA + (long)64*DH_;
        if (last){
            qa_h = *(const bf16x8*)(q2h + qoffA);
            qa_m = *(const bf16x8*)(q2m + qoffA);
            qb_h = *(const bf16x8*)(q2h + qoffB);
            qb_m = *(const bf16x8*)(q2m + qoffB);
        } else {
            qa_h = *(const bf16x8*)(qh3 + qoffA);
            qa_m = *(const bf16x8*)(qm3 + qoffA);
            qa_l = *(const bf16x8*)(ql3 + qoffA);
            qb_h = *(const bf16x8*)(qh3 + qoffB);
            qb_m = *(const bf16x8*)(qm3 + qoffB);
            qb_l = *(const bf16x8*)(ql3 + qoffB);
        }
    }

    float mA[4] = {-INFINITY,-INFINITY,-INFINITY,-INFINITY};
    float mB[4] = {-INFINITY,-INFINITY,-INFINITY,-INFINITY};
    float lsA[4] = {0.f,0.f,0.f,0.f};
    float lsB[4] = {0.f,0.f,0.f,0.f};
    f32x4 pvA[2], pvB[2];
    pvA[0] = (f32x4){0.f,0.f,0.f,0.f}; pvA[1] = (f32x4){0.f,0.f,0.f,0.f};
    pvB[0] = (f32x4){0.f,0.f,0.f,0.f}; pvB[1] = (f32x4){0.f,0.f,0.f,0.f};

    // preload pr=0 K-fragments (shared by both q-fragments)
    bf16x8 kAh[2], kAm[2], kAl[2];
    #pragma unroll
    for (int u = 0; u < 2; u++){
        long koff = kb + (long)(u*16 + mrow)*DH_ + quad*8;
        if (last){
            kAh[u] = *(const bf16x8*)(k2h + koff);
            kAm[u] = *(const bf16x8*)(k2m + koff);
        } else {
            kAh[u] = *(const bf16x8*)(kh3 + koff);
            kAm[u] = *(const bf16x8*)(km3 + koff);
            kAl[u] = *(const bf16x8*)(kl3 + koff);
        }
    }

    for (int pr = 0; pr < 32; pr++){
        // prefetch next pr's K-fragments
        bf16x8 kBh[2], kBm[2], kBl[2];
        if (pr < 31){
            #pragma unroll
            for (int u = 0; u < 2; u++){
                long koff = kb + (long)(((pr+1)*2+u)*16 + mrow)*DH_ + quad*8;
                if (last){
                    kBh[u] = *(const bf16x8*)(k2h + koff);
                    kBm[u] = *(const bf16x8*)(k2m + koff);
                } else {
                    kBh[u] = *(const bf16x8*)(kh3 + koff);
                    kBm[u] = *(const bf16x8*)(km3 + koff);
                    kBl[u] = *(const bf16x8*)(kl3 + koff);
                }
            }
        }
        // PV xT loads (shared by both fragments), hoisted above softmax
        bf16x8 xh8[2], xl8[2];
        if (!last){
            int j0 = pr*32;
            #pragma unroll
            for (int nt = 0; nt < 2; nt++){
                long xoff = ((long)(b*DIM_) + h*DH_ + nt*16 + mrow)*L_ + j0 + quad*8;
                xh8[nt] = *(const bf16x8*)(xTh + xoff);
                xl8[nt] = *(const bf16x8*)(xTm + xoff);
            }
        }
        // QK^T: both fragments against the same K fragments
        f32x4 accA[2], accB[2];
        #pragma unroll
        for (int u = 0; u < 2; u++){
            f32x4 a1 = (f32x4){0.f,0.f,0.f,0.f};
            f32x4 a2 = (f32x4){0.f,0.f,0.f,0.f};
            f32x4 b1 = (f32x4){0.f,0.f,0.f,0.f};
            f32x4 b2 = (f32x4){0.f,0.f,0.f,0.f};
            if (last){
                a1 = MFMA(qa_m, kAh[u], a1);
                a1 = MFMA(qa_h, kAm[u], a1);
                a2 = MFMA(qa_h, kAh[u], a2);
                b1 = MFMA(qb_m, kAh[u], b1);
                b1 = MFMA(qb_h, kAm[u], b1);
                b2 = MFMA(qb_h, kAh[u], b2);
            } else {
                a1 = MFMA(qa_l, kAh[u], a1);
                a1 = MFMA(qa_m, kAm[u], a1);
                a1 = MFMA(qa_h, kAl[u], a1);
                a2 = MFMA(qa_m, kAh[u], a2);
                a2 = MFMA(qa_h, kAm[u], a2);
                a2 = MFMA(qa_h, kAh[u], a2);
                b1 = MFMA(qb_l, kAh[u], b1);
                b1 = MFMA(qb_m, kAm[u], b1);
                b1 = MFMA(qb_h, kAl[u], b1);
                b2 = MFMA(qb_m, kAh[u], b2);
                b2 = MFMA(qb_h, kAm[u], b2);
                b2 = MFMA(qb_h, kAh[u], b2);
            }
            accA[u] = a1 + a2;
            accB[u] = b1 + b2;
        }
        // ---- frag A softmax (own ballot: trajectory == 1-frag version) ----
        {
            float tmv[4];
            #pragma unroll
            for (int r = 0; r < 4; r++){
                float tm = fmaxf(accA[0][r], accA[1][r]);
                tm = fmaxf(tm, __shfl_xor(tm, 1, 64));
                tm = fmaxf(tm, __shfl_xor(tm, 2, 64));
                tm = fmaxf(tm, __shfl_xor(tm, 4, 64));
                tm = fmaxf(tm, __shfl_xor(tm, 8, 64));
                tmv[r] = tm;
            }
            bool need = (tmv[0] > mA[0] + 32.f) | (tmv[1] > mA[1] + 32.f)
                      | (tmv[2] > mA[2] + 32.f) | (tmv[3] > mA[3] + 32.f);
            if (__ballot(need)){
                #pragma unroll
                for (int r = 0; r < 4; r++){
                    float mnew = fmaxf(mA[r], tmv[r]);
                    float sc = __expf((mA[r] - mnew) * inv32);
                    lsA[r] *= sc; pvA[0][r] *= sc; pvA[1][r] *= sc;
                    mA[r] = mnew;
                }
            }
            #pragma unroll
            for (int r = 0; r < 4; r++){
                float p0 = __expf((accA[0][r] - mA[r]) * inv32);
                float p1 = __expf((accA[1][r] - mA[r]) * inv32);
                lsA[r] += p0 + p1;
                if (!last){
                    pt[w][quad*4 + r][mrow]      = p0;
                    pt[w][quad*4 + r][16 + mrow] = p1;
                }
            }
        }
        // ---- frag B softmax ----
        {
            float tmv[4];
            #pragma unroll
            for (int r = 0; r < 4; r++){
                float tm = fmaxf(accB[0][r], accB[1][r]);
                tm = fmaxf(tm, __shfl_xor(tm, 1, 64));
                tm = fmaxf(tm, __shfl_xor(tm, 2, 64));
                tm = fmaxf(tm, __shfl_xor(tm, 4, 64));
                tm = fmaxf(tm, __shfl_xor(tm, 8, 64));
                tmv[r] = tm;
            }
            bool need = (tmv[0] > mB[0] + 32.f) | (tmv[1] > mB[1] + 32.f)
                      | (tmv[2] > mB[2] + 32.f) | (tmv[3] > mB[3] + 32.f);
            if (__ballot(need)){
                #pragma unroll
                for (int r = 0; r < 4; r++){
                    float mnew = fmaxf(mB[r], tmv[r]);
                    float sc = __expf((mB[r] - mnew) * inv32);
                    lsB[r] *= sc; pvB[0][r] *= sc; pvB[1][r] *= sc;
                    mB[r] = mnew;
                }
            }
            #pragma unroll
            for (int r = 0; r < 4; r++){
                float p0 = __expf((accB[0][r] - mB[r]) * inv32);
                float p1 = __expf((accB[1][r] - mB[r]) * inv32);
                lsB[r] += p0 + p1;
                if (!last){
                    pt[w][16 + quad*4 + r][mrow]      = p0;
                    pt[w][16 + quad*4 + r][16 + mrow] = p1;
                }
            }
        }
        if (!last){
            // per-wave LDS tiles: same-wave write->read is in-order (lgkmcnt)
            {   // frag A PV
                const float* pp = &pt[w][mrow][quad*8];
                bf16x8 phi, plo;
                #pragma unroll
                for (int jj = 0; jj < 8; jj++){
                    short hh, ll; split2(pp[jj], hh, ll);
                    phi[jj] = hh; plo[jj] = ll;
                }
                #pragma unroll
                for (int nt = 0; nt < 2; nt++){
                    pvA[nt] = MFMA(plo, xh8[nt], pvA[nt]);
                    pvA[nt] = MFMA(phi, xl8[nt], pvA[nt]);
                    pvA[nt] = MFMA(phi, xh8[nt], pvA[nt]);
                }
            }
            {   // frag B PV
                const float* pp = &pt[w][16 + mrow][quad*8];
                bf16x8 phi, plo;
                #pragma unroll
                for (int jj = 0; jj < 8; jj++){
                    short hh, ll; split2(pp[jj], hh, ll);
                    phi[jj] = hh; plo[jj] = ll;
                }
                #pragma unroll
                for (int nt = 0; nt < 2; nt++){
                    pvB[nt] = MFMA(plo, xh8[nt], pvB[nt]);
                    pvB[nt] = MFMA(phi, xl8[nt], pvB[nt]);
                    pvB[nt] = MFMA(phi, xh8[nt], pvB[nt]);
                }
            }
        }
        if (pr < 31){
            #pragma unroll
            for (int u = 0; u < 2; u++){
                kAh[u] = kBh[u]; kAm[u] = kBm[u];
                if (!last) kAl[u] = kBl[u];
            }
        }
    }
    #pragma unroll
    for (int r = 0; r < 4; r++){
        lsA[r] += __shfl_xor(lsA[r], 1, 64);
        lsA[r] += __shfl_xor(lsA[r], 2, 64);
        lsA[r] += __shfl_xor(lsA[r], 4, 64);
        lsA[r] += __shfl_xor(lsA[r], 8, 64);
        lsB[r] += __shfl_xor(lsB[r], 1, 64);
        lsB[r] += __shfl_xor(lsB[r], 2, 64);
        lsB[r] += __shfl_xor(lsB[r], 4, 64);
        lsB[r] += __shfl_xor(lsB[r], 8, 64);
    }
    float liA[4], liB[4];
    #pragma unroll
    for (int r = 0; r < 4; r++){ liA[r] = 1.0f / lsA[r]; liB[r] = 1.0f / lsB[r]; }

    if (!last){
        // mv (= PV/l + resid) -> LDS; frag A rows [0,64), frag B rows [64,128)
        #pragma unroll
        for (int nt = 0; nt < 2; nt++)
        #pragma unroll
        for (int r = 0; r < 4; r++){
            int lrow = w*16 + quad*4 + r;
            long rowA = s0 + quad*4 + r;
            float residA = xn[((long)(b*L_) + rowA)*DIM_ + h*DH_ + nt*16 + mrow];
            mv_lds[lrow][nt*16 + mrow] = pvA[nt][r]*liA[r] + residA;
            long rowB = rowA + 64;
            float residB = xn[((long)(b*L_) + rowB)*DIM_ + h*DH_ + nt*16 + mrow];
            mv_lds[64 + lrow][nt*16 + mrow] = pvB[nt][r]*liB[r] + residB;
        }
        __syncthreads();
        // v2 = gelu(relu(mv @ v_w + v_b)); out col j; 16 rows per thread
        const int j = lane & 31, rh = lane >> 5;
        float wreg[32];
        #pragma unroll
        for (int d = 0; d < 32; d++) wreg[d] = wv[d][j];
        const float vbj = vb[j];
        #pragma unroll
        for (int rr = 0; rr < 16; rr++){
            int lrow = w*16 + rh*8 + (rr & 7) + (rr >> 3)*64;
            const float* mp = &mv_lds[lrow][0];
            float a = vbj;
            #pragma unroll
            for (int d = 0; d < 32; d += 4){
                f32x4 m4 = *(const f32x4*)(mp + d);
                a += m4[0]*wreg[d] + m4[1]*wreg[d+1] + m4[2]*wreg[d+2] + m4[3]*wreg[d+3];
            }
            a = geluf(fmaxf(a, 0.f));
            int l = blockIdx.x*128 + lrow;
            long idx = ((long)(b*L_) + l)*DIM_ + h*DH_ + j;
            short hh2, mm2, ll2; split3(a, hh2, mm2, ll2);
            v2h[idx] = hh2; v2m[idx] = mm2; v2l[idx] = ll2;
        }
    } else {
        // recompute pass: 2-deep prefetch; K loads shared by both fragments.
        // Same per-row MFMA sequence as pass 1 -> bitwise-identical scores.
        long koff0 = kb + (long)mrow*DH_ + quad*8;
        bf16x8 h0 = *(const bf16x8*)(k2h + koff0);
        bf16x8 m0 = *(const bf16x8*)(k2m + koff0);
        bf16x8 h1 = *(const bf16x8*)(k2h + koff0 + 16*DH_);
        bf16x8 m1 = *(const bf16x8*)(k2m + koff0 + 16*DH_);
        for (int ct = 0; ct < 64; ct += 2){
            bf16x8 h2, m2, h3, m3;
            if (ct + 2 < 64){
                long ko2 = kb + (long)((ct+2)*16 + mrow)*DH_ + quad*8;
                h2 = *(const bf16x8*)(k2h + ko2);
                m2 = *(const bf16x8*)(k2m + ko2);
                h3 = *(const bf16x8*)(k2h + ko2 + 16*DH_);
                m3 = *(const bf16x8*)(k2m + ko2 + 16*DH_);
            }
            {
                f32x4 a1 = (f32x4){0.f,0.f,0.f,0.f};
                f32x4 a2 = (f32x4){0.f,0.f,0.f,0.f};
                a1 = MFMA(qa_m, h0, a1);
                a1 = MFMA(qa_h, m0, a1);
                a2 = MFMA(qa_h, h0, a2);
                f32x4 a = a1 + a2;
                f32x4 b1 = (f32x4){0.f,0.f,0.f,0.f};
                f32x4 b2 = (f32x4){0.f,0.f,0.f,0.f};
                b1 = MFMA(qb_m, h0, b1);
                b1 = MFMA(qb_h, m0, b1);
                b2 = MFMA(qb_h, h0, b2);
                f32x4 bb = b1 + b2;
                #pragma unroll
                for (int r = 0; r < 4; r++){
                    float pnA = __expf((a[r] - mA[r]) * inv32) * liA[r];
                    attn_out[((long)bh*L_ + s0 + quad*4 + r)*L_ + ct*16 + mrow] = pnA;
                    float pnB = __expf((bb[r] - mB[r]) * inv32) * liB[r];
                    attn_out[((long)bh*L_ + s0 + 64 + quad*4 + r)*L_ + ct*16 + mrow] = pnB;
                }
            }
            {
                f32x4 a1 = (f32x4){0.f,0.f,0.f,0.f};
                f32x4 a2 = (f32x4){0.f,0.f,0.f,0.f};
                a1 = MFMA(qa_m, h1, a1);
                a1 = MFMA(qa_h, m1, a1);
                a2 = MFMA(qa_h, h1, a2);
                f32x4 a = a1 + a2;
                f32x4 b1 = (f32x4){0.f,0.f,0.f,0.f};
                f32x4 b2 = (f32x4){0.f,0.f,0.f,0.f};
                b1 = MFMA(qb_m, h1, b1);
                b1 = MFMA(qb_h, m1, b1);
                b2 = MFMA(qb_h, h1, b2);
                f32x4 bb = b1 + b2;
                #pragma unroll
                for (int r = 0; r < 4; r++){
                    float pnA = __expf((a[r] - mA[r]) * inv32) * liA[r];
                    attn_out[((long)bh*L_ + s0 + quad*4 + r)*L_ + (ct+1)*16 + mrow] = pnA;
                    float pnB = __expf((bb[r] - mB[r]) * inv32) * liB[r];
                    attn_out[((long)bh*L_ + s0 + 64 + quad*4 + r)*L_ + (ct+1)*16 + mrow] = pnB;
                }
            }
            if (ct + 2 < 64){ h0 = h2; m0 = m2; h1 = h3; m1 = m3; }
        }
    }
}

extern "C" void kernel_launch(void* const* d_in, const int* in_sizes, int n_in,
                              void* d_out, int out_size, void* d_ws, size_t ws_size,
                              hipStream_t stream)
{
    const int o = (n_in >= 16) ? 3 : 2;
    const void* img    = d_in[0];
    const void* adj    = d_in[1];
    const void* conv_w = d_in[o+0];
    const void* conv_b = d_in[o+1];
    const void* bn_g   = d_in[o+2];
    const void* bn_b   = d_in[o+3];
    const void* emb_w  = d_in[o+4];
    const void* emb_b  = d_in[o+5];
    const void* ln_g   = d_in[o+6];
    const void* ln_b   = d_in[o+7];
    const void* qk_w   = d_in[o+8];
    const void* qk_b   = d_in[o+9];
    const void* v_w    = d_in[o+10];
    const void* v_b    = d_in[o+11];
    const void* proj_w = d_in[o+12];
    float* attn_out = (float*)d_out;   // reference output dtype = float32

    // d_out scratch (64M floats). Lifetimes: pre-loop {x0,psum,embT,pT},
    // loop {xn,xT,q3,k3,v2}; pT persists through the loop (read-only).
    // INVARIANT: final attn writes ALL of d_out and reads ONLY d_ws (q2/k2).
    float* S = (float*)d_out;
    const long M1 = 1L << 20;
    float* x     = S;                      // 0..2M (permanent)
    float* xn    = S + 2*M1;               // 2..4M (loop)
    short* sp    = (short*)(S + 6*M1);     // permanent shorts: adj splits, embT
    short* adjh  = sp;
    short* adjm  = sp + 1*M1;
    short* adjl  = sp + 2*M1;
    short* embTh = sp + 3*M1;              // 256K each (pre-loop)
    short* embTm = embTh + 262144;
    short* embTl = embTm + 262144;
    short* lp    = (short*)(S + 8*M1);     // loop shorts pool (floats 8..20.3M)
    short* xTh   = lp;                     // 2M shorts each
    short* xTm   = lp + 2*M1;
    short* xTl   = lp + 4*M1;
    short* qh3   = lp + 6*M1;
    short* qm3   = lp + 8*M1;
    short* ql3   = lp + 10*M1;
    short* kh3   = lp + 12*M1;
    short* km3   = lp + 14*M1;
    short* kl3   = lp + 16*M1;
    short* v2h   = lp + 18*M1;
    short* v2m   = lp + 20*M1;
    short* v2l   = lp + 22*M1;
    short* pTh   = lp + 24*M1;             // 64K x 3 layers each (pre-computed)
    short* pTm   = pTh + 3*65536;
    short* pTl   = pTm + 3*65536;
    float* psum  = S + 24*M1;              // pre-loop only (past loop pool+pT)
    float* psq   = psum + (long)EC_*NPATCH;
    short* x0h   = (short*)(S + 41*M1);    // 8M shorts each -> floats 41..53M
    short* x0m   = x0h + 8*M1;
    short* x0l   = x0m + 8*M1;

    float* wsf   = (float*)d_ws;           // ws use: 16 MB + 1 KB (proven size)
    int*   flag  = (int*)wsf;
    float* scaleA= wsf + 64;
    float* biasA = wsf + 128;
    short* q2h   = (short*)(wsf + 256);    // 2M shorts (4 MB) each: last-layer
    short* q2m   = q2h + 2*M1;             // q/k 2-term splits (16 MB total)
    short* k2h   = q2m + 2*M1;
    short* k2m   = k2h + 2*M1;

    detect_kernel<<<1, 64, 0, stream>>>(img, flag);
    split_adj_kernel<<<L_*L_/256, 256, 0, stream>>>(flag, adj, adjh, adjm, adjl);
    tsplit_kernel<<<dim3(4,16,1), 256, 0, stream>>>(flag, emb_w, 0, 0, PD_, DIM_,
                                                    embTh, embTm, embTl, 0);
    // all 3 layers' proj_w transposed splits in one dispatch (z = layer)
    tsplit_kernel<<<dim3(4,4,3), 256, 0, stream>>>(flag, proj_w, 0, (long)DIM_*DIM_,
                                                   DIM_, DIM_, pTh, pTm, pTl, 65536);
    conv_stats_kernel<<<NPATCH, 256, 0, stream>>>(flag, img, conv_w, conv_b, psum, psq);
    bn_stats_kernel<<<EC_, 256, 0, stream>>>(flag, psum, psq, bn_g, bn_b, scaleA, biasA);
    bn_gelu_pool_kernel<<<NPATCH, 256, 0, stream>>>(flag, img, conv_w, conv_b,
                                                    scaleA, biasA, x0h, x0m, x0l);

    // x = x0 @ emb_w + emb_b   (8192x1024 @ 1024x256) via MFMA splits
    mfma_gemm<<<dim3(2,256,1), 256, 0, stream>>>(
        x0h, x0m, x0l, 0,  embTh, embTm, embTl, 0,
        emb_b, 0, flag,  nullptr, 0,  x, 0,  DIM_, PD_);

    for (int i = 0; i < DEPTH_; i++){
        const bool last = (i == DEPTH_-1);
        ln_repack_kernel<<<NROWS/32/8, 256, 0, stream>>>(flag, x,
            ln_g, (long)i*DIM_, ln_b, (long)i*DIM_, xn, xTh, xTm, xTl);
        // m = A @ xn + xn (LDS-resident) -> qk = relu(m @ qk_w + qk_b)
        gemm_axn_qk<<<dim3(2,32,8), 256, 0, stream>>>(
            adjh, adjm, adjl,  xTh, xTm, xTl,  xn, flag,
            qk_w, (long)i*DH_*2*DH_, qk_b, (long)i*2*DH_,
            qh3, qm3, ql3, kh3, km3, kl3,
            last ? q2h : nullptr, last ? q2m : nullptr,
            last ? k2h : nullptr, last ? k2m : nullptr);
        attn_mfma_kernel<<<dim3(8, B_*HEADS_), 256, 0, stream>>>(
            qh3, qm3, ql3, kh3, km3, kl3, q2h, q2m, k2h, k2m,
            xTh, xTm, xn, flag,
            v_w, (long)i*DH_*DH_, v_b, (long)i*DH_,
            v2h, v2m, v2l,
            last ? attn_out : nullptr);
        if (!last){
            // x = v2 @ proj_w + xn  (pT pre-computed for this layer)
            mfma_gemm<<<dim3(2,256,1), 256, 0, stream>>>(
                v2h, v2m, v2l, 0,
                pTh + (long)i*65536, pTm + (long)i*65536, pTl + (long)i*65536, 0,
                nullptr, 0, flag,  xn, 0,  x, 0,  DIM_, DIM_);
        }
    }
}

// Round 14
// 1462.824 us; speedup vs baseline: 1.1892x; 1.1086x over previous
//
#include <hip/hip_runtime.h>
#include <hip/hip_bf16.h>
#include <math.h>

typedef __hip_bfloat16 bf16;
typedef __attribute__((ext_vector_type(8))) short bf16x8;
typedef __attribute__((ext_vector_type(4))) float f32x4;

#define MFMA(a,b,c) __builtin_amdgcn_mfma_f32_16x16x32_bf16(a,b,c,0,0,0)

#define B_ 8
#define C_ 3
#define IMG_ 512
#define P_ 16
#define DIM_ 256
#define HEADS_ 8
#define DEPTH_ 4
#define DH_ 32
#define L_ 1024
#define EC_ 64
#define PD_ 1024
#define NPATCH 8192
#define NROWS 65536

__device__ __forceinline__ float ldsel(const void* p, long i, int m){
    return m ? __bfloat162float(((const bf16*)p)[i]) : ((const float*)p)[i];
}
__device__ __forceinline__ float geluf(float x){
    return 0.5f * x * (1.0f + erff(x * 0.70710678118654752f));
}
__device__ __forceinline__ short f2bf_s(float f){
    bf16 h = __float2bfloat16(f); return *(short*)&h;
}
__device__ __forceinline__ float bfs2f(short s){
    bf16 h = *(bf16*)&s; return __bfloat162float(h);
}
__device__ __forceinline__ void split2(float f, short& hi, short& lo){
    hi = f2bf_s(f);
    lo = f2bf_s(f - bfs2f(hi));
}
__device__ __forceinline__ void split3(float f, short& h, short& m, short& l){
    h = f2bf_s(f); float r1 = f - bfs2f(h);
    m = f2bf_s(r1); float r2 = r1 - bfs2f(m);
    l = f2bf_s(r2);
}

// Runtime input-dtype detection (bf16 vs fp32): exponent-byte histogram.
__global__ void detect_kernel(const void* __restrict__ img, int* __restrict__ flag)
{
    const unsigned* w = (const unsigned*)img;
    const int t = threadIdx.x;
    int c = 0;
    #pragma unroll
    for (int i = 0; i < 4; i++){
        unsigned b = (w[t*4 + i] >> 7) & 0xFFu;
        if (b >= 100u && b <= 145u) c++;
    }
    #pragma unroll
    for (int o = 32; o > 0; o >>= 1) c += __shfl_xor(c, o, 64);
    if (t == 0) *flag = (c > 180) ? 1 : 0;
}

// ---------------------------------------------------------------------------
// Conv stats pass: lane = output channel (broadcast inp reads, conflict-free),
// zero-padded 18x18 tile (branch-free, bitwise-identical conv values).
// ---------------------------------------------------------------------------
__global__ void conv_stats_kernel(const int* __restrict__ fl,
                                  const void* __restrict__ img,
                                  const void* __restrict__ conv_w,
                                  const void* __restrict__ conv_b,
                                  float* __restrict__ psum, float* __restrict__ psq)
{
    const int f = *fl;
    __shared__ float inp[3*18*18];
    __shared__ float wl[EC_*27];
    __shared__ float reds[4][64], redq[4][64];
    const int n = blockIdx.x, t = threadIdx.x;
    const int b = n >> 10, l = n & 1023;
    const int gy = l >> 5, gx = l & 31;
    const int w = t >> 6, o = t & 63;
    for (int e = t; e < EC_*27; e += 256) wl[e] = ldsel(conv_w, e, f);
    for (int e = t; e < 3*18*18; e += 256){
        int c = e / 324, rem = e - c*324;
        int y = rem / 18, x = rem - y*18;
        float v = 0.f;
        if (y >= 1 && y <= 16 && x >= 1 && x <= 16)
            v = ldsel(img, ((long)(b*C_+c)*IMG_ + gy*P_ + (y-1))*IMG_ + gx*P_ + (x-1), f);
        inp[e] = v;
    }
    __syncthreads();
    float wr[27];
    #pragma unroll
    for (int i = 0; i < 27; i++) wr[i] = wl[o*27 + i];
    const float cb = ldsel(conv_b, o, f);
    float s = 0.f, sq = 0.f;
    #pragma unroll
    for (int i = 0; i < 16; i++){
        int pix = w*16 + i;
        int oy = pix >> 3, ox = pix & 7;
        float acc = cb;
        #pragma unroll
        for (int c = 0; c < 3; c++)
        #pragma unroll
        for (int ky = 0; ky < 3; ky++)
        #pragma unroll
        for (int kx = 0; kx < 3; kx++)
            acc += inp[c*324 + (2*oy+ky)*18 + 2*ox+kx] * wr[c*9+ky*3+kx];
        s += acc; sq += acc*acc;
    }
    reds[w][o] = s; redq[w][o] = sq;
    __syncthreads();
    if (t < 64){
        float S = reds[0][t]+reds[1][t]+reds[2][t]+reds[3][t];
        float Q = redq[0][t]+redq[1][t]+redq[2][t]+redq[3][t];
        psum[(long)t*NPATCH + n] = S;
        psq [(long)t*NPATCH + n] = Q;
    }
}

__global__ void bn_stats_kernel(const int* __restrict__ fl,
                                const float* __restrict__ psum, const float* __restrict__ psq,
                                const void* __restrict__ bn_g, const void* __restrict__ bn_b,
                                float* __restrict__ scaleA, float* __restrict__ biasA)
{
    const int f = *fl;
    __shared__ float rs[256], rq[256];
    const int o = blockIdx.x, t = threadIdx.x;
    float S = 0.f, Q = 0.f;
    for (int n = t; n < NPATCH; n += 256){ S += psum[(long)o*NPATCH+n]; Q += psq[(long)o*NPATCH+n]; }
    rs[t] = S; rq[t] = Q; __syncthreads();
    for (int st = 128; st > 0; st >>= 1){
        if (t < st){ rs[t] += rs[t+st]; rq[t] += rq[t+st]; }
        __syncthreads();
    }
    if (t == 0){
        const float Ninv = 1.0f / (float)((long)NPATCH * 64);
        float mean = rs[0] * Ninv;
        float var  = rq[0] * Ninv - mean*mean;
        float rstd = rsqrtf(var + 1e-5f);
        float sc = ldsel(bn_g, o, f) * rstd;
        scaleA[o] = sc;
        biasA[o]  = ldsel(bn_b, o, f) - mean*sc;
    }
}

// Recompute conv (bitwise-identical), BN + exact GELU + maxpool; emits x0 splits.
__global__ void bn_gelu_pool_kernel(const int* __restrict__ fl,
                                    const void* __restrict__ img,
                                    const void* __restrict__ conv_w,
                                    const void* __restrict__ conv_b,
                                    const float* __restrict__ scaleA,
                                    const float* __restrict__ biasA,
                                    short* __restrict__ x0h, short* __restrict__ x0m,
                                    short* __restrict__ x0l)
{
    const int f = *fl;
    __shared__ float inp[3*18*18];
    __shared__ float wl[EC_*27];
    __shared__ float cosb[64][65];
    __shared__ float poolb[64*17];
    __shared__ float sA[64], bA[64];
    const int n = blockIdx.x, t = threadIdx.x;
    const int b = n >> 10, l = n & 1023;
    const int gy = l >> 5, gx = l & 31;
    const int w = t >> 6, o = t & 63;
    for (int e = t; e < EC_*27; e += 256) wl[e] = ldsel(conv_w, e, f);
    for (int e = t; e < 3*18*18; e += 256){
        int c = e / 324, rem = e - c*324;
        int y = rem / 18, x = rem - y*18;
        float v = 0.f;
        if (y >= 1 && y <= 16 && x >= 1 && x <= 16)
            v = ldsel(img, ((long)(b*C_+c)*IMG_ + gy*P_ + (y-1))*IMG_ + gx*P_ + (x-1), f);
        inp[e] = v;
    }
    if (t < 64){ sA[t] = scaleA[t]; bA[t] = biasA[t]; }
    __syncthreads();
    float wr[27];
    #pragma unroll
    for (int i = 0; i < 27; i++) wr[i] = wl[o*27 + i];
    const float cb = ldsel(conv_b, o, f);
    const float sc = sA[o], bb = bA[o];
    #pragma unroll
    for (int i = 0; i < 16; i++){
        int pix = w*16 + i;
        int oy = pix >> 3, ox = pix & 7;
        float acc = cb;
        #pragma unroll
        for (int c = 0; c < 3; c++)
        #pragma unroll
        for (int ky = 0; ky < 3; ky++)
        #pragma unroll
        for (int kx = 0; kx < 3; kx++)
            acc += inp[c*324 + (2*oy+ky)*18 + 2*ox+kx] * wr[c*9+ky*3+kx];
        cosb[pix][o] = geluf(acc*sc + bb);
    }
    __syncthreads();
    #pragma unroll
    for (int j = 0; j < 4; j++){
        int pp = w*4 + j;
        int py = pp >> 2, px = pp & 3;
        int y0 = max(0, 2*py-1), y1 = min(7, 2*py+1);
        int xs = max(0, 2*px-1), x1 = min(7, 2*px+1);
        float mx = -INFINITY;
        for (int y = y0; y <= y1; y++)
            for (int x = xs; x <= x1; x++)
                mx = fmaxf(mx, cosb[y*8+x][o]);
        poolb[o*17 + pp] = mx;
    }
    __syncthreads();
    for (int e = t; e < 1024; e += 256){
        float v = poolb[(e>>4)*17 + (e&15)];
        short h, m, lo; split3(v, h, m, lo);
        long idx = (long)n*PD_ + e;
        x0h[idx] = h; x0m[idx] = m; x0l[idx] = lo;
    }
}

// Elementwise 3-term split (adjacency).
__global__ void split_adj_kernel(const int* __restrict__ fl, const void* __restrict__ adj,
                                 short* __restrict__ Ah, short* __restrict__ Am,
                                 short* __restrict__ Al)
{
    const int f = *fl;
    long i = (long)blockIdx.x*256 + threadIdx.x;
    short h, m, l; split3(ldsel(adj, i, f), h, m, l);
    Ah[i] = h; Am[i] = m; Al[i] = l;
}

// Transpose + 3-term split: out[c][r] = src[r][c].  grid (C/64, R/64, Z).
__global__ void tsplit_kernel(const int* __restrict__ fl, const void* __restrict__ src,
                              long soff, long zsStride, int R, int Ccols,
                              short* __restrict__ oh, short* __restrict__ om,
                              short* __restrict__ ol, long ozStride)
{
    __shared__ float tile[64][65];
    const int f = *fl;
    const int t = threadIdx.x;
    const int zz = blockIdx.z;
    const long sb = soff + (long)zz*zsStride;
    oh += (long)zz*ozStride; om += (long)zz*ozStride; ol += (long)zz*ozStride;
    const int c0 = blockIdx.x*64, r0 = blockIdx.y*64;
    for (int e = t; e < 4096; e += 256){
        int r = e >> 6, c = e & 63;
        tile[r][c] = ldsel(src, sb + (long)(r0+r)*Ccols + c0+c, f);
    }
    __syncthreads();
    const int ch = t >> 2, lg = t & 3;
    long ob = (long)(c0+ch)*R + r0 + lg*16;
    bf16x8 h0,h1,m0,m1,l0,l1;
    #pragma unroll
    for (int i = 0; i < 8; i++){
        short h,m,l;
        split3(tile[lg*16+i][ch], h,m,l);    h0[i]=h; m0[i]=m; l0[i]=l;
        split3(tile[lg*16+8+i][ch], h,m,l);  h1[i]=h; m1[i]=m; l1[i]=l;
    }
    *(bf16x8*)(oh+ob) = h0; *(bf16x8*)(oh+ob+8) = h1;
    *(bf16x8*)(om+ob) = m0; *(bf16x8*)(om+ob+8) = m1;
    *(bf16x8*)(ol+ob) = l0; *(bf16x8*)(ol+ob+8) = l1;
}

// ---------------------------------------------------------------------------
// Fused LayerNorm + transpose-split: x (rows of 256) -> xn fp32 row-major AND
// xT (b,256,L) 3-term splits.  32 rows/block, 256 blocks.
// ---------------------------------------------------------------------------
__global__ void ln_repack_kernel(const int* __restrict__ fl,
                                 const float* __restrict__ x,
                                 const void* __restrict__ g, long goff,
                                 const void* __restrict__ beta, long boff,
                                 float* __restrict__ xn,
                                 short* __restrict__ xTh, short* __restrict__ xTm,
                                 short* __restrict__ xTl)
{
    __shared__ float tile[32][257];
    __shared__ float gs[256], bs[256];
    __shared__ float pm[8][32], pq[8][32];
    __shared__ float mean_s[32], rstd_s[32];
    const int f = *fl;
    const int t = threadIdx.x;
    const int r0 = blockIdx.x*32;            // global row (b*L + l)
    const int b = r0 >> 10, l0 = r0 & 1023;
    gs[t] = ldsel(g, goff + t, f);
    bs[t] = ldsel(beta, boff + t, f);
    for (int e = t; e < 32*256; e += 256){
        int r = e >> 8, c = e & 255;
        tile[r][c] = x[(long)(r0+r)*DIM_ + c];
    }
    __syncthreads();
    {
        int row = t & 31, part = t >> 5;
        float s = 0.f, q = 0.f;
        #pragma unroll
        for (int c = 0; c < 32; c++){
            float v = tile[row][part*32 + c];
            s += v; q += v*v;
        }
        pm[part][row] = s; pq[part][row] = q;
    }
    __syncthreads();
    if (t < 32){
        float S = 0.f, Q = 0.f;
        #pragma unroll
        for (int p2 = 0; p2 < 8; p2++){ S += pm[p2][t]; Q += pq[p2][t]; }
        float mean = S * (1.0f/256.0f);
        float var  = Q * (1.0f/256.0f) - mean*mean;
        mean_s[t] = mean;
        rstd_s[t] = rsqrtf(var + 1e-5f);
    }
    __syncthreads();
    for (int e = t; e < 32*256; e += 256){
        int r = e >> 8, c = e & 255;
        float v = (tile[r][c] - mean_s[r])*rstd_s[r]*gs[c] + bs[c];
        tile[r][c] = v;
        xn[(long)(r0+r)*DIM_ + c] = v;
    }
    __syncthreads();
    // transposed split emit: 2 passes of 128 cols; 2 lanes cover the 32 rows
    const int half = t & 1, cB = t >> 1;
    #pragma unroll
    for (int gp = 0; gp < 2; gp++){
        int c = gp*128 + cB;
        long ob = ((long)(b*DIM_) + c)*L_ + l0 + half*16;
        bf16x8 h0, m0, l0v;
        #pragma unroll
        for (int i = 0; i < 8; i++){
            short hh, mm, ll;
            split3(tile[half*16 + i][c], hh, mm, ll);
            h0[i]=hh; m0[i]=mm; l0v[i]=ll;
        }
        *(bf16x8*)(xTh+ob) = h0; *(bf16x8*)(xTm+ob) = m0; *(bf16x8*)(xTl+ob) = l0v;
        bf16x8 h1, m1, l1v;
        #pragma unroll
        for (int i = 0; i < 8; i++){
            short hh, mm, ll;
            split3(tile[half*16 + 8 + i][c], hh, mm, ll);
            h1[i]=hh; m1[i]=mm; l1v[i]=ll;
        }
        *(bf16x8*)(xTh+ob+8) = h1; *(bf16x8*)(xTm+ob+8) = m1; *(bf16x8*)(xTl+ob+8) = l1v;
    }
}

// ---------------------------------------------------------------------------
// Generic MFMA GEMM, fp32-accurate via 3-term bf16 splits (6 products).
// Tile 64 rows x 64 cols; 4 waves = 2 row-strips x 2 col-halves; each wave
// 32x32 = 2 A-frags x 2 B-frags: 24 MFMA per 12 load-packets (intensity 2.0
// vs 1.6 at 16x64/wave; B-panel traffic halves).  Grid stays 512 blocks
// (2 blocks/CU) for emb/proj.  Register ping-pong double-buffer; K%64==0.
// Per-output K/product order unchanged -> bitwise-identical results.
// ---------------------------------------------------------------------------
__global__ __launch_bounds__(256)
void mfma_gemm(const short* __restrict__ Ah, const short* __restrict__ Am,
               const short* __restrict__ Al, long strAb,
               const short* __restrict__ Bh, const short* __restrict__ Bm,
               const short* __restrict__ Bl, long strBb,
               const void* __restrict__ bias, long biasOff, const int* __restrict__ fl,
               const float* __restrict__ Dadd, long strDb,
               float* __restrict__ C, long strCb,
               int N, int K)
{
    const int t = threadIdx.x;
    const int w = t >> 6, lane = t & 63;
    const int mrow = lane & 15, quad = lane >> 4;
    const int wr = w & 1, wc = w >> 1;
    const int s0 = blockIdx.y*64 + wr*32;
    const int n0 = blockIdx.x*64 + wc*32;
    const int z = blockIdx.z;
    const short* Ahp = Ah + (long)z*strAb;
    const short* Amp = Am + (long)z*strAb;
    const short* Alp = Al + (long)z*strAb;
    const short* Bhp = Bh + (long)z*strBb;
    const short* Bmp = Bm + (long)z*strBb;
    const short* Blp = Bl + (long)z*strBb;
    f32x4 acc[2][2];
    #pragma unroll
    for (int i = 0; i < 2; i++)
    #pragma unroll
    for (int j = 0; j < 2; j++) acc[i][j] = (f32x4){0.f,0.f,0.f,0.f};

    const long a0 = (long)(s0 + mrow)*K + quad*8;
    const long b0 = (long)(n0 + mrow)*K + quad*8;
    const long fstp = (long)16*K;

    bf16x8 ahA[2], amA[2], alA[2], bhA[2], bmA[2], blA[2];
    #pragma unroll
    for (int i = 0; i < 2; i++){
        ahA[i] = *(const bf16x8*)(Ahp + a0 + i*fstp);
        amA[i] = *(const bf16x8*)(Amp + a0 + i*fstp);
        alA[i] = *(const bf16x8*)(Alp + a0 + i*fstp);
        bhA[i] = *(const bf16x8*)(Bhp + b0 + i*fstp);
        bmA[i] = *(const bf16x8*)(Bmp + b0 + i*fstp);
        blA[i] = *(const bf16x8*)(Blp + b0 + i*fstp);
    }
    for (int k0 = 0; k0 < K; k0 += 64){
        bf16x8 ahB[2], amB[2], alB[2], bhB[2], bmB[2], blB[2];
        #pragma unroll
        for (int i = 0; i < 2; i++){
            long an = a0 + i*fstp + k0 + 32;
            long bn = b0 + i*fstp + k0 + 32;
            ahB[i] = *(const bf16x8*)(Ahp + an);
            amB[i] = *(const bf16x8*)(Amp + an);
            alB[i] = *(const bf16x8*)(Alp + an);
            bhB[i] = *(const bf16x8*)(Bhp + bn);
            bmB[i] = *(const bf16x8*)(Bmp + bn);
            blB[i] = *(const bf16x8*)(Blp + bn);
        }
        #pragma unroll
        for (int ai = 0; ai < 2; ai++)
        #pragma unroll
        for (int bj = 0; bj < 2; bj++){
            acc[ai][bj] = MFMA(alA[ai], bhA[bj], acc[ai][bj]);
            acc[ai][bj] = MFMA(amA[ai], bmA[bj], acc[ai][bj]);
            acc[ai][bj] = MFMA(ahA[ai], blA[bj], acc[ai][bj]);
            acc[ai][bj] = MFMA(amA[ai], bhA[bj], acc[ai][bj]);
            acc[ai][bj] = MFMA(ahA[ai], bmA[bj], acc[ai][bj]);
            acc[ai][bj] = MFMA(ahA[ai], bhA[bj], acc[ai][bj]);
        }
        if (k0 + 64 < K){
            #pragma unroll
            for (int i = 0; i < 2; i++){
                long an = a0 + i*fstp + k0 + 64;
                long bn = b0 + i*fstp + k0 + 64;
                ahA[i] = *(const bf16x8*)(Ahp + an);
                amA[i] = *(const bf16x8*)(Amp + an);
                alA[i] = *(const bf16x8*)(Alp + an);
                bhA[i] = *(const bf16x8*)(Bhp + bn);
                bmA[i] = *(const bf16x8*)(Bmp + bn);
                blA[i] = *(const bf16x8*)(Blp + bn);
            }
        }
        #pragma unroll
        for (int ai = 0; ai < 2; ai++)
        #pragma unroll
        for (int bj = 0; bj < 2; bj++){
            acc[ai][bj] = MFMA(alB[ai], bhB[bj], acc[ai][bj]);
            acc[ai][bj] = MFMA(amB[ai], bmB[bj], acc[ai][bj]);
            acc[ai][bj] = MFMA(ahB[ai], blB[bj], acc[ai][bj]);
            acc[ai][bj] = MFMA(amB[ai], bhB[bj], acc[ai][bj]);
            acc[ai][bj] = MFMA(ahB[ai], bmB[bj], acc[ai][bj]);
            acc[ai][bj] = MFMA(ahB[ai], bhB[bj], acc[ai][bj]);
        }
    }
    const int f = *fl;
    #pragma unroll
    for (int ai = 0; ai < 2; ai++)
    #pragma unroll
    for (int bj = 0; bj < 2; bj++)
    #pragma unroll
    for (int r = 0; r < 4; r++){
        long row = s0 + ai*16 + quad*4 + r;
        int col = n0 + bj*16 + mrow;
        float v = acc[ai][bj][r];
        if (bias) v += ldsel(bias, biasOff + col, f);
        if (Dadd) v += Dadd[(long)z*strDb + row*N + col];
        C[(long)z*strCb + row*N + col] = v;
    }
}

// ---------------------------------------------------------------------------
// Fused A@xn GEMM + qk projection.  m = adj @ xn + xn stays in LDS.
// Tile 64 rows x 64 cols (= 2 heads); wave = 32x32 = 2 A-frags x 2 B-frags
// (24 MFMA / 12 packets); register ping-pong.  grid (4,16,8) = 512 blocks.
// Epilogue: wave w -> head blockIdx.x*2+(w&1), rows (w>>1)*32..+32.
// Non-last: emits q/k 3-term splits. Last: 2-term splits into d_ws
// (INVARIANT: last-layer attn reads only d_ws).
// ---------------------------------------------------------------------------
__global__ __launch_bounds__(256)
void gemm_axn_qk(const short* __restrict__ Ah, const short* __restrict__ Am,
                 const short* __restrict__ Al,
                 const short* __restrict__ Bh, const short* __restrict__ Bm,
                 const short* __restrict__ Bl,
                 const float* __restrict__ xn, const int* __restrict__ fl,
                 const void* __restrict__ qk_w, long woff,
                 const void* __restrict__ qk_b, long boff,
                 short* __restrict__ qh, short* __restrict__ qm, short* __restrict__ ql,
                 short* __restrict__ kh, short* __restrict__ km, short* __restrict__ kl,
                 short* __restrict__ q2h, short* __restrict__ q2m,
                 short* __restrict__ k2h, short* __restrict__ k2m)
{
    __shared__ float m_lds[64][68];
    __shared__ float wl[32][65];
    __shared__ float bl2[64];
    const int t = threadIdx.x;
    const int w = t >> 6, lane = t & 63;
    const int mrow = lane & 15, quad = lane >> 4;
    const int wr = w & 1, wc = w >> 1;
    const int s0 = blockIdx.y*64 + wr*32;    // wave row base within L
    const int n0 = blockIdx.x*64;            // block col base (64 cols = 2 heads)
    const int nc = n0 + wc*32;               // wave col base
    const int z = blockIdx.z;                // batch
    const int f = *fl;
    for (int e = t; e < 2048; e += 256) wl[e>>6][e&63] = ldsel(qk_w, woff + e, f);
    if (t < 64) bl2[t] = ldsel(qk_b, boff + t, f);

    const short* Bhp = Bh + (long)z*DIM_*L_;
    const short* Bmp = Bm + (long)z*DIM_*L_;
    const short* Blp = Bl + (long)z*DIM_*L_;
    f32x4 acc[2][2];
    #pragma unroll
    for (int i = 0; i < 2; i++)
    #pragma unroll
    for (int j = 0; j < 2; j++) acc[i][j] = (f32x4){0.f,0.f,0.f,0.f};

    const long a0 = (long)(s0 + mrow)*L_ + quad*8;
    const long b0 = (long)(nc + mrow)*L_ + quad*8;
    const long fstp = (long)16*L_;

    bf16x8 ahA[2], amA[2], alA[2], bhA[2], bmA[2], blA[2];
    #pragma unroll
    for (int i = 0; i < 2; i++){
        ahA[i] = *(const bf16x8*)(Ah + a0 + i*fstp);
        amA[i] = *(const bf16x8*)(Am + a0 + i*fstp);
        alA[i] = *(const bf16x8*)(Al + a0 + i*fstp);
        bhA[i] = *(const bf16x8*)(Bhp + b0 + i*fstp);
        bmA[i] = *(const bf16x8*)(Bmp + b0 + i*fstp);
        blA[i] = *(const bf16x8*)(Blp + b0 + i*fstp);
    }
    for (int k0 = 0; k0 < L_; k0 += 64){
        bf16x8 ahB[2], amB[2], alB[2], bhB[2], bmB[2], blB[2];
        #pragma unroll
        for (int i = 0; i < 2; i++){
            long an = a0 + i*fstp + k0 + 32;
            long bn = b0 + i*fstp + k0 + 32;
            ahB[i] = *(const bf16x8*)(Ah + an);
            amB[i] = *(const bf16x8*)(Am + an);
            alB[i] = *(const bf16x8*)(Al + an);
            bhB[i] = *(const bf16x8*)(Bhp + bn);
            bmB[i] = *(const bf16x8*)(Bmp + bn);
            blB[i] = *(const bf16x8*)(Blp + bn);
        }
        #pragma unroll
        for (int ai = 0; ai < 2; ai++)
        #pragma unroll
        for (int bj = 0; bj < 2; bj++){
            acc[ai][bj] = MFMA(alA[ai], bhA[bj], acc[ai][bj]);
            acc[ai][bj] = MFMA(amA[ai], bmA[bj], acc[ai][bj]);
            acc[ai][bj] = MFMA(ahA[ai], blA[bj], acc[ai][bj]);
            acc[ai][bj] = MFMA(amA[ai], bhA[bj], acc[ai][bj]);
            acc[ai][bj] = MFMA(ahA[ai], bmA[bj], acc[ai][bj]);
            acc[ai][bj] = MFMA(ahA[ai], bhA[bj], acc[ai][bj]);
        }
        if (k0 + 64 < L_){
            #pragma unroll
            for (int i = 0; i < 2; i++){
                long an = a0 + i*fstp + k0 + 64;
                long bn = b0 + i*fstp + k0 + 64;
                ahA[i] = *(const bf16x8*)(Ah + an);
                amA[i] = *(const bf16x8*)(Am + an);
                alA[i] = *(const bf16x8*)(Al + an);
                bhA[i] = *(const bf16x8*)(Bhp + bn);
                bmA[i] = *(const bf16x8*)(Bmp + bn);
                blA[i] = *(const bf16x8*)(Blp + bn);
            }
        }
        #pragma unroll
        for (int ai = 0; ai < 2; ai++)
        #pragma unroll
        for (int bj = 0; bj < 2; bj++){
            acc[ai][bj] = MFMA(alB[ai], bhB[bj], acc[ai][bj]);
            acc[ai][bj] = MFMA(amB[ai], bmB[bj], acc[ai][bj]);
            acc[ai][bj] = MFMA(ahB[ai], blB[bj], acc[ai][bj]);
            acc[ai][bj] = MFMA(amB[ai], bhB[bj], acc[ai][bj]);
            acc[ai][bj] = MFMA(ahB[ai], bmB[bj], acc[ai][bj]);
            acc[ai][bj] = MFMA(ahB[ai], bhB[bj], acc[ai][bj]);
        }
    }
    // m tile (with residual) -> LDS
    #pragma unroll
    for (int ai = 0; ai < 2; ai++)
    #pragma unroll
    for (int bj = 0; bj < 2; bj++)
    #pragma unroll
    for (int r = 0; r < 4; r++){
        long row = s0 + ai*16 + quad*4 + r;
        int col = nc + bj*16 + mrow;
        m_lds[wr*32 + ai*16 + quad*4 + r][wc*32 + bj*16 + mrow] =
            acc[ai][bj][r] + xn[((long)(z*L_) + row)*DIM_ + col];
    }
    __syncthreads();
    // qk epilogue: wave w -> head blockIdx.x*2+(w&1); rows (w>>1)*32..+32
    const int j = lane;
    float wreg[32];
    #pragma unroll
    for (int d = 0; d < 32; d++) wreg[d] = wl[d][j];
    const float bj2 = bl2[j];
    const int hl = w & 1, rh = w >> 1;
    const int hgl = blockIdx.x*2 + hl;       // global head
    #pragma unroll
    for (int rr = 0; rr < 32; rr++){
        const int lrow = rh*32 + rr;
        const float* mp = &m_lds[lrow][hl*32];
        float a = bj2;
        #pragma unroll
        for (int d = 0; d < 32; d += 4){
            f32x4 m4 = *(const f32x4*)(mp + d);
            a += m4[0]*wreg[d] + m4[1]*wreg[d+1] + m4[2]*wreg[d+2] + m4[3]*wreg[d+3];
        }
        a = fmaxf(a, 0.f);
        long rg = ((long)(z*HEADS_ + hgl))*L_ + blockIdx.y*64 + lrow;
        if (q2h){
            short hh2, mm2; split2(a, hh2, mm2);
            if (j < 32){ q2h[rg*DH_+j]=hh2; q2m[rg*DH_+j]=mm2; }
            else { int d2 = j-32; k2h[rg*DH_+d2]=hh2; k2m[rg*DH_+d2]=mm2; }
        } else {
            short hh2, mm2, ll2; split3(a, hh2, mm2, ll2);
            if (j < 32){ qh[rg*DH_+j]=hh2; qm[rg*DH_+j]=mm2; ql[rg*DH_+j]=ll2; }
            else { int d2 = j-32; kh[rg*DH_+d2]=hh2; km[rg*DH_+d2]=mm2; kl[rg*DH_+d2]=ll2; }
        }
    }
}

// ---------------------------------------------------------------------------
// MFMA attention, 2 q-fragments per wave (rows s0 and s0+64) sharing the
// K-fragment and xT loads (R13-measured best).  Per-16-row-group defer-max
// ballots kept SEPARATE per fragment -> bitwise-identical outputs.
// grid (8, 64) = 512 blocks.
// Non-last: q/k 3-term, 6-product scores, online pass, fused v2 epilogue.
// Last: q/k 2-term from d_ws; 3-product scores; online pass then recompute
// pass (2-deep prefetch, K loads shared across both fragments).
// ---------------------------------------------------------------------------
__global__ __launch_bounds__(256)
void attn_mfma_kernel(const short* __restrict__ qh3, const short* __restrict__ qm3,
                      const short* __restrict__ ql3,
                      const short* __restrict__ kh3, const short* __restrict__ km3,
                      const short* __restrict__ kl3,
                      const short* __restrict__ q2h, const short* __restrict__ q2m,
                      const short* __restrict__ k2h, const short* __restrict__ k2m,
                      const short* __restrict__ xTh, const short* __restrict__ xTm,
                      const float* __restrict__ xn, const int* __restrict__ fl,
                      const void* __restrict__ v_w, long vwoff,
                      const void* __restrict__ v_b, long vboff,
                      short* __restrict__ v2h, short* __restrict__ v2m,
                      short* __restrict__ v2l,
                      float* __restrict__ attn_out)
{
    __shared__ float pt[4][32][37];
    __shared__ float mv_lds[128][36];
    __shared__ float wv[32][33];
    __shared__ float vb[32];
    const int t = threadIdx.x;
    const int w = t >> 6, lane = t & 63;
    const int mrow = lane & 15, quad = lane >> 4;
    const int bh = blockIdx.y, b = bh >> 3, h = bh & 7;
    const int s0 = blockIdx.x*128 + w*16;    // frag A rows; frag B = s0+64
    const bool last = (attn_out != nullptr);
    const float inv32 = 1.0f/32.0f;
    const long kb = (long)bh*L_*DH_;

    if (!last){
        const int f = *fl;
        for (int e = t; e < 1024; e += 256) wv[e>>5][e&31] = ldsel(v_w, vwoff + e, f);
        if (t < 32) vb[t] = ldsel(v_b, vboff + t, f);
    }

    bf16x8 qa_h, qa_m, qa_l, qb_h, qb_m, qb_l;
    {
        long qoffA = ((long)bh*L_ + s0 + mrow)*DH_ + quad*8;
        long qoffB = qoffA + (long)64*DH_;
        if (last){
            qa_h = *(const bf16x8*)(q2h + qoffA);
            qa_m = *(const bf16x8*)(q2m + qoffA);
            qb_h = *(const bf16x8*)(q2h + qoffB);
            qb_m = *(const bf16x8*)(q2m + qoffB);
        } else {
            qa_h = *(const bf16x8*)(qh3 + qoffA);
            qa_m = *(const bf16x8*)(qm3 + qoffA);
            qa_l = *(const bf16x8*)(ql3 + qoffA);
            qb_h = *(const bf16x8*)(qh3 + qoffB);
            qb_m = *(const bf16x8*)(qm3 + qoffB);
            qb_l = *(const bf16x8*)(ql3 + qoffB);
        }
    }

    float mA[4] = {-INFINITY,-INFINITY,-INFINITY,-INFINITY};
    float mB[4] = {-INFINITY,-INFINITY,-INFINITY,-INFINITY};
    float lsA[4] = {0.f,0.f,0.f,0.f};
    float lsB[4] = {0.f,0.f,0.f,0.f};
    f32x4 pvA[2], pvB[2];
    pvA[0] = (f32x4){0.f,0.f,0.f,0.f}; pvA[1] = (f32x4){0.f,0.f,0.f,0.f};
    pvB[0] = (f32x4){0.f,0.f,0.f,0.f}; pvB[1] = (f32x4){0.f,0.f,0.f,0.f};

    // preload pr=0 K-fragments (shared by both q-fragments)
    bf16x8 kAh[2], kAm[2], kAl[2];
    #pragma unroll
    for (int u = 0; u < 2; u++){
        long koff = kb + (long)(u*16 + mrow)*DH_ + quad*8;
        if (last){
            kAh[u] = *(const bf16x8*)(k2h + koff);
            kAm[u] = *(const bf16x8*)(k2m + koff);
        } else {
            kAh[u] = *(const bf16x8*)(kh3 + koff);
            kAm[u] = *(const bf16x8*)(km3 + koff);
            kAl[u] = *(const bf16x8*)(kl3 + koff);
        }
    }

    for (int pr = 0; pr < 32; pr++){
        // prefetch next pr's K-fragments
        bf16x8 kBh[2], kBm[2], kBl[2];
        if (pr < 31){
            #pragma unroll
            for (int u = 0; u < 2; u++){
                long koff = kb + (long)(((pr+1)*2+u)*16 + mrow)*DH_ + quad*8;
                if (last){
                    kBh[u] = *(const bf16x8*)(k2h + koff);
                    kBm[u] = *(const bf16x8*)(k2m + koff);
                } else {
                    kBh[u] = *(const bf16x8*)(kh3 + koff);
                    kBm[u] = *(const bf16x8*)(km3 + koff);
                    kBl[u] = *(const bf16x8*)(kl3 + koff);
                }
            }
        }
        // PV xT loads (shared by both fragments), hoisted above softmax
        bf16x8 xh8[2], xl8[2];
        if (!last){
            int j0 = pr*32;
            #pragma unroll
            for (int nt = 0; nt < 2; nt++){
                long xoff = ((long)(b*DIM_) + h*DH_ + nt*16 + mrow)*L_ + j0 + quad*8;
                xh8[nt] = *(const bf16x8*)(xTh + xoff);
                xl8[nt] = *(const bf16x8*)(xTm + xoff);
            }
        }
        // QK^T: both fragments against the same K fragments
        f32x4 accA[2], accB[2];
        #pragma unroll
        for (int u = 0; u < 2; u++){
            f32x4 a1 = (f32x4){0.f,0.f,0.f,0.f};
            f32x4 a2 = (f32x4){0.f,0.f,0.f,0.f};
            f32x4 b1 = (f32x4){0.f,0.f,0.f,0.f};
            f32x4 b2 = (f32x4){0.f,0.f,0.f,0.f};
            if (last){
                a1 = MFMA(qa_m, kAh[u], a1);
                a1 = MFMA(qa_h, kAm[u], a1);
                a2 = MFMA(qa_h, kAh[u], a2);
                b1 = MFMA(qb_m, kAh[u], b1);
                b1 = MFMA(qb_h, kAm[u], b1);
                b2 = MFMA(qb_h, kAh[u], b2);
            } else {
                a1 = MFMA(qa_l, kAh[u], a1);
                a1 = MFMA(qa_m, kAm[u], a1);
                a1 = MFMA(qa_h, kAl[u], a1);
                a2 = MFMA(qa_m, kAh[u], a2);
                a2 = MFMA(qa_h, kAm[u], a2);
                a2 = MFMA(qa_h, kAh[u], a2);
                b1 = MFMA(qb_l, kAh[u], b1);
                b1 = MFMA(qb_m, kAm[u], b1);
                b1 = MFMA(qb_h, kAl[u], b1);
                b2 = MFMA(qb_m, kAh[u], b2);
                b2 = MFMA(qb_h, kAm[u], b2);
                b2 = MFMA(qb_h, kAh[u], b2);
            }
            accA[u] = a1 + a2;
            accB[u] = b1 + b2;
        }
        // ---- frag A softmax (own ballot: trajectory == 1-frag version) ----
        {
            float tmv[4];
            #pragma unroll
            for (int r = 0; r < 4; r++){
                float tm = fmaxf(accA[0][r], accA[1][r]);
                tm = fmaxf(tm, __shfl_xor(tm, 1, 64));
                tm = fmaxf(tm, __shfl_xor(tm, 2, 64));
                tm = fmaxf(tm, __shfl_xor(tm, 4, 64));
                tm = fmaxf(tm, __shfl_xor(tm, 8, 64));
                tmv[r] = tm;
            }
            bool need = (tmv[0] > mA[0] + 32.f) | (tmv[1] > mA[1] + 32.f)
                      | (tmv[2] > mA[2] + 32.f) | (tmv[3] > mA[3] + 32.f);
            if (__ballot(need)){
                #pragma unroll
                for (int r = 0; r < 4; r++){
                    float mnew = fmaxf(mA[r], tmv[r]);
                    float sc = __expf((mA[r] - mnew) * inv32);
                    lsA[r] *= sc; pvA[0][r] *= sc; pvA[1][r] *= sc;
                    mA[r] = mnew;
                }
            }
            #pragma unroll
            for (int r = 0; r < 4; r++){
                float p0 = __expf((accA[0][r] - mA[r]) * inv32);
                float p1 = __expf((accA[1][r] - mA[r]) * inv32);
                lsA[r] += p0 + p1;
                if (!last){
                    pt[w][quad*4 + r][mrow]      = p0;
                    pt[w][quad*4 + r][16 + mrow] = p1;
                }
            }
        }
        // ---- frag B softmax ----
        {
            float tmv[4];
            #pragma unroll
            for (int r = 0; r < 4; r++){
                float tm = fmaxf(accB[0][r], accB[1][r]);
                tm = fmaxf(tm, __shfl_xor(tm, 1, 64));
                tm = fmaxf(tm, __shfl_xor(tm, 2, 64));
                tm = fmaxf(tm, __shfl_xor(tm, 4, 64));
                tm = fmaxf(tm, __shfl_xor(tm, 8, 64));
                tmv[r] = tm;
            }
            bool need = (tmv[0] > mB[0] + 32.f) | (tmv[1] > mB[1] + 32.f)
                      | (tmv[2] > mB[2] + 32.f) | (tmv[3] > mB[3] + 32.f);
            if (__ballot(need)){
                #pragma unroll
                for (int r = 0; r < 4; r++){
                    float mnew = fmaxf(mB[r], tmv[r]);
                    float sc = __expf((mB[r] - mnew) * inv32);
                    lsB[r] *= sc; pvB[0][r] *= sc; pvB[1][r] *= sc;
                    mB[r] = mnew;
                }
            }
            #pragma unroll
            for (int r = 0; r < 4; r++){
                float p0 = __expf((accB[0][r] - mB[r]) * inv32);
                float p1 = __expf((accB[1][r] - mB[r]) * inv32);
                lsB[r] += p0 + p1;
                if (!last){
                    pt[w][16 + quad*4 + r][mrow]      = p0;
                    pt[w][16 + quad*4 + r][16 + mrow] = p1;
                }
            }
        }
        if (!last){
            // per-wave LDS tiles: same-wave write->read is in-order (lgkmcnt)
            {   // frag A PV
                const float* pp = &pt[w][mrow][quad*8];
                bf16x8 phi, plo;
                #pragma unroll
                for (int jj = 0; jj < 8; jj++){
                    short hh, ll; split2(pp[jj], hh, ll);
                    phi[jj] = hh; plo[jj] = ll;
                }
                #pragma unroll
                for (int nt = 0; nt < 2; nt++){
                    pvA[nt] = MFMA(plo, xh8[nt], pvA[nt]);
                    pvA[nt] = MFMA(phi, xl8[nt], pvA[nt]);
                    pvA[nt] = MFMA(phi, xh8[nt], pvA[nt]);
                }
            }
            {   // frag B PV
                const float* pp = &pt[w][16 + mrow][quad*8];
                bf16x8 phi, plo;
                #pragma unroll
                for (int jj = 0; jj < 8; jj++){
                    short hh, ll; split2(pp[jj], hh, ll);
                    phi[jj] = hh; plo[jj] = ll;
                }
                #pragma unroll
                for (int nt = 0; nt < 2; nt++){
                    pvB[nt] = MFMA(plo, xh8[nt], pvB[nt]);
                    pvB[nt] = MFMA(phi, xl8[nt], pvB[nt]);
                    pvB[nt] = MFMA(phi, xh8[nt], pvB[nt]);
                }
            }
        }
        if (pr < 31){
            #pragma unroll
            for (int u = 0; u < 2; u++){
                kAh[u] = kBh[u]; kAm[u] = kBm[u];
                if (!last) kAl[u] = kBl[u];
            }
        }
    }
    #pragma unroll
    for (int r = 0; r < 4; r++){
        lsA[r] += __shfl_xor(lsA[r], 1, 64);
        lsA[r] += __shfl_xor(lsA[r], 2, 64);
        lsA[r] += __shfl_xor(lsA[r], 4, 64);
        lsA[r] += __shfl_xor(lsA[r], 8, 64);
        lsB[r] += __shfl_xor(lsB[r], 1, 64);
        lsB[r] += __shfl_xor(lsB[r], 2, 64);
        lsB[r] += __shfl_xor(lsB[r], 4, 64);
        lsB[r] += __shfl_xor(lsB[r], 8, 64);
    }
    float liA[4], liB[4];
    #pragma unroll
    for (int r = 0; r < 4; r++){ liA[r] = 1.0f / lsA[r]; liB[r] = 1.0f / lsB[r]; }

    if (!last){
        // mv (= PV/l + resid) -> LDS; frag A rows [0,64), frag B rows [64,128)
        #pragma unroll
        for (int nt = 0; nt < 2; nt++)
        #pragma unroll
        for (int r = 0; r < 4; r++){
            int lrow = w*16 + quad*4 + r;
            long rowA = s0 + quad*4 + r;
            float residA = xn[((long)(b*L_) + rowA)*DIM_ + h*DH_ + nt*16 + mrow];
            mv_lds[lrow][nt*16 + mrow] = pvA[nt][r]*liA[r] + residA;
            long rowB = rowA + 64;
            float residB = xn[((long)(b*L_) + rowB)*DIM_ + h*DH_ + nt*16 + mrow];
            mv_lds[64 + lrow][nt*16 + mrow] = pvB[nt][r]*liB[r] + residB;
        }
        __syncthreads();
        // v2 = gelu(relu(mv @ v_w + v_b)); out col j; 16 rows per thread
        const int j = lane & 31, rh = lane >> 5;
        float wreg[32];
        #pragma unroll
        for (int d = 0; d < 32; d++) wreg[d] = wv[d][j];
        const float vbj = vb[j];
        #pragma unroll
        for (int rr = 0; rr < 16; rr++){
            int lrow = w*16 + rh*8 + (rr & 7) + (rr >> 3)*64;
            const float* mp = &mv_lds[lrow][0];
            float a = vbj;
            #pragma unroll
            for (int d = 0; d < 32; d += 4){
                f32x4 m4 = *(const f32x4*)(mp + d);
                a += m4[0]*wreg[d] + m4[1]*wreg[d+1] + m4[2]*wreg[d+2] + m4[3]*wreg[d+3];
            }
            a = geluf(fmaxf(a, 0.f));
            int l = blockIdx.x*128 + lrow;
            long idx = ((long)(b*L_) + l)*DIM_ + h*DH_ + j;
            short hh2, mm2, ll2; split3(a, hh2, mm2, ll2);
            v2h[idx] = hh2; v2m[idx] = mm2; v2l[idx] = ll2;
        }
    } else {
        // recompute pass: 2-deep prefetch; K loads shared by both fragments.
        // Same per-row MFMA sequence as pass 1 -> bitwise-identical scores.
        long koff0 = kb + (long)mrow*DH_ + quad*8;
        bf16x8 h0 = *(const bf16x8*)(k2h + koff0);
        bf16x8 m0 = *(const bf16x8*)(k2m + koff0);
        bf16x8 h1 = *(const bf16x8*)(k2h + koff0 + 16*DH_);
        bf16x8 m1 = *(const bf16x8*)(k2m + koff0 + 16*DH_);
        for (int ct = 0; ct < 64; ct += 2){
            bf16x8 h2, m2, h3, m3;
            if (ct + 2 < 64){
                long ko2 = kb + (long)((ct+2)*16 + mrow)*DH_ + quad*8;
                h2 = *(const bf16x8*)(k2h + ko2);
                m2 = *(const bf16x8*)(k2m + ko2);
                h3 = *(const bf16x8*)(k2h + ko2 + 16*DH_);
                m3 = *(const bf16x8*)(k2m + ko2 + 16*DH_);
            }
            {
                f32x4 a1 = (f32x4){0.f,0.f,0.f,0.f};
                f32x4 a2 = (f32x4){0.f,0.f,0.f,0.f};
                a1 = MFMA(qa_m, h0, a1);
                a1 = MFMA(qa_h, m0, a1);
                a2 = MFMA(qa_h, h0, a2);
                f32x4 a = a1 + a2;
                f32x4 b1 = (f32x4){0.f,0.f,0.f,0.f};
                f32x4 b2 = (f32x4){0.f,0.f,0.f,0.f};
                b1 = MFMA(qb_m, h0, b1);
                b1 = MFMA(qb_h, m0, b1);
                b2 = MFMA(qb_h, h0, b2);
                f32x4 bb = b1 + b2;
                #pragma unroll
                for (int r = 0; r < 4; r++){
                    float pnA = __expf((a[r] - mA[r]) * inv32) * liA[r];
                    attn_out[((long)bh*L_ + s0 + quad*4 + r)*L_ + ct*16 + mrow] = pnA;
                    float pnB = __expf((bb[r] - mB[r]) * inv32) * liB[r];
                    attn_out[((long)bh*L_ + s0 + 64 + quad*4 + r)*L_ + ct*16 + mrow] = pnB;
                }
            }
            {
                f32x4 a1 = (f32x4){0.f,0.f,0.f,0.f};
                f32x4 a2 = (f32x4){0.f,0.f,0.f,0.f};
                a1 = MFMA(qa_m, h1, a1);
                a1 = MFMA(qa_h, m1, a1);
                a2 = MFMA(qa_h, h1, a2);
                f32x4 a = a1 + a2;
                f32x4 b1 = (f32x4){0.f,0.f,0.f,0.f};
                f32x4 b2 = (f32x4){0.f,0.f,0.f,0.f};
                b1 = MFMA(qb_m, h1, b1);
                b1 = MFMA(qb_h, m1, b1);
                b2 = MFMA(qb_h, h1, b2);
                f32x4 bb = b1 + b2;
                #pragma unroll
                for (int r = 0; r < 4; r++){
                    float pnA = __expf((a[r] - mA[r]) * inv32) * liA[r];
                    attn_out[((long)bh*L_ + s0 + quad*4 + r)*L_ + (ct+1)*16 + mrow] = pnA;
                    float pnB = __expf((bb[r] - mB[r]) * inv32) * liB[r];
                    attn_out[((long)bh*L_ + s0 + 64 + quad*4 + r)*L_ + (ct+1)*16 + mrow] = pnB;
                }
            }
            if (ct + 2 < 64){ h0 = h2; m0 = m2; h1 = h3; m1 = m3; }
        }
    }
}

extern "C" void kernel_launch(void* const* d_in, const int* in_sizes, int n_in,
                              void* d_out, int out_size, void* d_ws, size_t ws_size,
                              hipStream_t stream)
{
    const int o = (n_in >= 16) ? 3 : 2;
    const void* img    = d_in[0];
    const void* adj    = d_in[1];
    const void* conv_w = d_in[o+0];
    const void* conv_b = d_in[o+1];
    const void* bn_g   = d_in[o+2];
    const void* bn_b   = d_in[o+3];
    const void* emb_w  = d_in[o+4];
    const void* emb_b  = d_in[o+5];
    const void* ln_g   = d_in[o+6];
    const void* ln_b   = d_in[o+7];
    const void* qk_w   = d_in[o+8];
    const void* qk_b   = d_in[o+9];
    const void* v_w    = d_in[o+10];
    const void* v_b    = d_in[o+11];
    const void* proj_w = d_in[o+12];
    float* attn_out = (float*)d_out;   // reference output dtype = float32

    // d_out scratch (64M floats). Lifetimes: pre-loop {x0,psum,embT,pT},
    // loop {xn,xT,q3,k3,v2}; pT persists through the loop (read-only).
    // INVARIANT: final attn writes ALL of d_out and reads ONLY d_ws (q2/k2).
    float* S = (float*)d_out;
    const long M1 = 1L << 20;
    float* x     = S;                      // 0..2M (permanent)
    float* xn    = S + 2*M1;               // 2..4M (loop)
    short* sp    = (short*)(S + 6*M1);     // permanent shorts: adj splits, embT
    short* adjh  = sp;
    short* adjm  = sp + 1*M1;
    short* adjl  = sp + 2*M1;
    short* embTh = sp + 3*M1;              // 256K each (pre-loop)
    short* embTm = embTh + 262144;
    short* embTl = embTm + 262144;
    short* lp    = (short*)(S + 8*M1);     // loop shorts pool (floats 8..20.3M)
    short* xTh   = lp;                     // 2M shorts each
    short* xTm   = lp + 2*M1;
    short* xTl   = lp + 4*M1;
    short* qh3   = lp + 6*M1;
    short* qm3   = lp + 8*M1;
    short* ql3   = lp + 10*M1;
    short* kh3   = lp + 12*M1;
    short* km3   = lp + 14*M1;
    short* kl3   = lp + 16*M1;
    short* v2h   = lp + 18*M1;
    short* v2m   = lp + 20*M1;
    short* v2l   = lp + 22*M1;
    short* pTh   = lp + 24*M1;             // 64K x 3 layers each (pre-computed)
    short* pTm   = pTh + 3*65536;
    short* pTl   = pTm + 3*65536;
    float* psum  = S + 24*M1;              // pre-loop only (past loop pool+pT)
    float* psq   = psum + (long)EC_*NPATCH;
    short* x0h   = (short*)(S + 41*M1);    // 8M shorts each -> floats 41..53M
    short* x0m   = x0h + 8*M1;
    short* x0l   = x0m + 8*M1;

    float* wsf   = (float*)d_ws;           // ws use: 16 MB + 1 KB (proven size)
    int*   flag  = (int*)wsf;
    float* scaleA= wsf + 64;
    float* biasA = wsf + 128;
    short* q2h   = (short*)(wsf + 256);    // 2M shorts (4 MB) each: last-layer
    short* q2m   = q2h + 2*M1;             // q/k 2-term splits (16 MB total)
    short* k2h   = q2m + 2*M1;
    short* k2m   = k2h + 2*M1;

    detect_kernel<<<1, 64, 0, stream>>>(img, flag);
    split_adj_kernel<<<L_*L_/256, 256, 0, stream>>>(flag, adj, adjh, adjm, adjl);
    tsplit_kernel<<<dim3(4,16,1), 256, 0, stream>>>(flag, emb_w, 0, 0, PD_, DIM_,
                                                    embTh, embTm, embTl, 0);
    // all 3 layers' proj_w transposed splits in one dispatch (z = layer)
    tsplit_kernel<<<dim3(4,4,3), 256, 0, stream>>>(flag, proj_w, 0, (long)DIM_*DIM_,
                                                   DIM_, DIM_, pTh, pTm, pTl, 65536);
    conv_stats_kernel<<<NPATCH, 256, 0, stream>>>(flag, img, conv_w, conv_b, psum, psq);
    bn_stats_kernel<<<EC_, 256, 0, stream>>>(flag, psum, psq, bn_g, bn_b, scaleA, biasA);
    bn_gelu_pool_kernel<<<NPATCH, 256, 0, stream>>>(flag, img, conv_w, conv_b,
                                                    scaleA, biasA, x0h, x0m, x0l);

    // x = x0 @ emb_w + emb_b   (8192x1024 @ 1024x256) via MFMA splits
    mfma_gemm<<<dim3(4,128,1), 256, 0, stream>>>(
        x0h, x0m, x0l, 0,  embTh, embTm, embTl, 0,
        emb_b, 0, flag,  nullptr, 0,  x, 0,  DIM_, PD_);

    for (int i = 0; i < DEPTH_; i++){
        const bool last = (i == DEPTH_-1);
        ln_repack_kernel<<<NROWS/32/8, 256, 0, stream>>>(flag, x,
            ln_g, (long)i*DIM_, ln_b, (long)i*DIM_, xn, xTh, xTm, xTl);
        // m = A @ xn + xn (LDS-resident) -> qk = relu(m @ qk_w + qk_b)
        gemm_axn_qk<<<dim3(4,16,8), 256, 0, stream>>>(
            adjh, adjm, adjl,  xTh, xTm, xTl,  xn, flag,
            qk_w, (long)i*DH_*2*DH_, qk_b, (long)i*2*DH_,
            qh3, qm3, ql3, kh3, km3, kl3,
            last ? q2h : nullptr, last ? q2m : nullptr,
            last ? k2h : nullptr, last ? k2m : nullptr);
        attn_mfma_kernel<<<dim3(8, B_*HEADS_), 256, 0, stream>>>(
            qh3, qm3, ql3, kh3, km3, kl3, q2h, q2m, k2h, k2m,
            xTh, xTm, xn, flag,
            v_w, (long)i*DH_*DH_, v_b, (long)i*DH_,
            v2h, v2m, v2l,
            last ? attn_out : nullptr);
        if (!last){
            // x = v2 @ proj_w + xn  (pT pre-computed for this layer)
            mfma_gemm<<<dim3(4,128,1), 256, 0, stream>>>(
                v2h, v2m, v2l, 0,
                pTh + (long)i*65536, pTm + (long)i*65536, pTl + (long)i*65536, 0,
                nullptr, 0, flag,  xn, 0,  x, 0,  DIM_, DIM_);
        }
    }
}